// Round 14
// baseline (545.917 us; speedup 1.0000x reference)
//
#include <hip/hip_runtime.h>
#include <math.h>

#define NN 20000
#define NE 160000
#define NG 1000
#define IND 11
#define H 128
#define ED 3
#define NL 5
#define ZDH (259*128)
#define BN_EPSF 1e-5f
#define BPAD 17   /* 16B-chunks per B-row in LDS (16 + 1 pad) */
#define EPW 16    /* edges per wave in agg_edge */

typedef unsigned short ushort_t;
typedef __attribute__((ext_vector_type(8))) short bf8_t;
typedef __attribute__((ext_vector_type(4))) float f4_t;

__device__ inline ushort_t f2bf(float x) {
    unsigned int u = __float_as_uint(x);
    unsigned int r = (u + 0x7fffu + ((u >> 16) & 1u)) >> 16;
    return (ushort_t)r;
}
__device__ inline float bf2f(ushort_t b) {
    return __uint_as_float(((unsigned int)b) << 16);
}

// ---------------- CSR build (once per call) ----------------

__global__ void deg_int_kernel(const int* __restrict__ dst, int* __restrict__ degi) {
    int e = blockIdx.x * blockDim.x + threadIdx.x;
    if (e < NE) atomicAdd(&degi[dst[e]], 1);
}

__global__ __launch_bounds__(256) void reserve_kernel(const int* __restrict__ degi,
                                                      int* __restrict__ cursor,
                                                      float* __restrict__ invdeg,
                                                      int* __restrict__ counter) {
    int n = blockIdx.x * blockDim.x + threadIdx.x;
    int lane = threadIdx.x & 63;
    int v = (n < NN) ? degi[n] : 0;
    int x = v;
#pragma unroll
    for (int st = 1; st < 64; st <<= 1) {
        int y = __shfl_up(x, st, 64);
        if (lane >= st) x += y;
    }
    int total = __shfl(x, 63, 64);
    int base = 0;
    if (lane == 63) base = atomicAdd(counter, total);
    base = __shfl(base, 63, 64);
    if (n < NN) {
        cursor[n] = base + x - v;
        invdeg[n] = 1.0f / (float)(v < 1 ? 1 : v);
    }
}

__global__ void scatter_kernel(const int* __restrict__ src, const int* __restrict__ dst,
                               const float* __restrict__ ea,
                               const float* __restrict__ invdeg,
                               int* __restrict__ cursor, float4* __restrict__ csr_ea4,
                               int* __restrict__ csr_dst, float* __restrict__ csr_inv) {
    int e = blockIdx.x * blockDim.x + threadIdx.x;
    if (e < NE) {
        int d = dst[e];
        int pos = atomicAdd(&cursor[d], 1);
        float4 r;
        r.x = ea[e * ED + 0];
        r.y = ea[e * ED + 1];
        r.z = ea[e * ED + 2];
        r.w = __int_as_float(src[e]);
        csr_ea4[pos] = r;
        csr_dst[pos] = d;
        csr_inv[pos] = invdeg[d];
    }
}

// marks the last CSR position of each dst-segment in a bitmask
__global__ void flag_kernel(const int* __restrict__ csr_dst, unsigned* __restrict__ endmask) {
    int e = blockIdx.x * blockDim.x + threadIdx.x;
    if (e < NE) {
        int d = csr_dst[e];
        int dn = (e + 1 < NE) ? csr_dst[e + 1] : -1;
        if (d != dn) atomicOr(&endmask[e >> 5], 1u << (e & 31));
    }
}

// ---------------- weight prep: transpose to [n][k] bf16 hi/lo ----------------
// table order: 0=Pf(Wf k<128), 1=Ps(Ws k<128), 2=Qf(Wf k>=128), 3=Qs(Ws k>=128)
__global__ void wprep_kernel(const float* __restrict__ Wf, const float* __restrict__ Ws,
                             ushort_t* __restrict__ Wt_hi, ushort_t* __restrict__ Wt_lo) {
    int idx = blockIdx.x * 256 + threadIdx.x;   // l*65536 + n*128 + k
    if (idx >= NL * 512 * H) return;
    int k = idx & 127;
    int n = (idx >> 7) & 511;
    int l = idx >> 16;
    int t = n >> 7, j = n & 127;
    const float* W = (t == 0 || t == 2) ? Wf : Ws;
    int krow = (t < 2) ? k : (H + k);
    float v = W[(size_t)l * ZDH + krow * H + j];
    ushort_t hi = f2bf(v);
    Wt_hi[idx] = hi;
    Wt_lo[idx] = f2bf(v - bf2f(hi));
}

// ---------------- network ----------------

__global__ __launch_bounds__(H) void hin_kernel(const float* __restrict__ x,
                                                const float* __restrict__ Win,
                                                const float* __restrict__ bin,
                                                float* __restrict__ h) {
    int n = blockIdx.x;
    int j = threadIdx.x;
    __shared__ float xr[IND];
    if (j < IND) xr[j] = x[n * IND + j];
    __syncthreads();
    float acc = bin[j];
#pragma unroll
    for (int k = 0; k < IND; ++k) acc = fmaf(xr[k], Win[k * H + j], acc);
    h[(size_t)n * H + j] = acc;
}

// MFMA node GEMM v5 (unchanged from R12): B staged in LDS once per block.
__global__ __launch_bounds__(256, 2) void node_gemm_mfma(const float* __restrict__ hsrc,
                                                         float* __restrict__ hbn,
                                                         const ushort_t* __restrict__ Wt_hi,
                                                         const ushort_t* __restrict__ Wt_lo,
                                                         const float* __restrict__ sum,
                                                         const float* __restrict__ sumsq,
                                                         const float* __restrict__ gamma,
                                                         const float* __restrict__ beta,
                                                         int applyBN,
                                                         float* __restrict__ tab0,
                                                         float* __restrict__ tab1,
                                                         float* __restrict__ tab2,
                                                         float* __restrict__ tab3) {
    __shared__ __align__(16) ushort_t lbHi[128 * BPAD * 8];
    __shared__ __align__(16) ushort_t lbLo[128 * BPAD * 8];
    int table = blockIdx.y;
    int wave = threadIdx.x >> 6;
    int lane = threadIdx.x & 63;
    int sub = lane & 15;
    int quad = lane >> 4;
    int m0 = blockIdx.x * 128 + wave * 32;
    int writeH = applyBN && (table == 0);

    const ushort_t* wh = Wt_hi + (size_t)table * 128 * H;
    const ushort_t* wl = Wt_lo + (size_t)table * 128 * H;

    for (int c = threadIdx.x; c < 2048; c += 256) {
        int n = c >> 4, k = c & 15;
        bf8_t vh = *(const bf8_t*)(wh + n * H + k * 8);
        bf8_t vl = *(const bf8_t*)(wl + n * H + k * 8);
        *(bf8_t*)(lbHi + ((size_t)n * BPAD + k) * 8) = vh;
        *(bf8_t*)(lbLo + ((size_t)n * BPAD + k) * 8) = vl;
    }

    bf8_t aHi[2][4], aLo[2][4];
#pragma unroll
    for (int ks = 0; ks < 4; ++ks) {
        int kb = ks * 32 + quad * 8;
        float sc8[8], sh8[8];
        if (applyBN) {
            float4 su0 = *(const float4*)&sum[kb],   su1 = *(const float4*)&sum[kb + 4];
            float4 sq0 = *(const float4*)&sumsq[kb], sq1 = *(const float4*)&sumsq[kb + 4];
            float4 ga0 = *(const float4*)&gamma[kb], ga1 = *(const float4*)&gamma[kb + 4];
            float4 be0 = *(const float4*)&beta[kb],  be1 = *(const float4*)&beta[kb + 4];
            float su[8] = {su0.x, su0.y, su0.z, su0.w, su1.x, su1.y, su1.z, su1.w};
            float sq[8] = {sq0.x, sq0.y, sq0.z, sq0.w, sq1.x, sq1.y, sq1.z, sq1.w};
            float ga[8] = {ga0.x, ga0.y, ga0.z, ga0.w, ga1.x, ga1.y, ga1.z, ga1.w};
            float be[8] = {be0.x, be0.y, be0.z, be0.w, be1.x, be1.y, be1.z, be1.w};
#pragma unroll
            for (int i = 0; i < 8; ++i) {
                float mu  = su[i] * (1.0f / NN);
                float var = sq[i] * (1.0f / NN) - mu * mu;
                sc8[i] = ga[i] * rsqrtf(var + BN_EPSF);
                sh8[i] = be[i] - mu * sc8[i];
            }
        }
#pragma unroll
        for (int mt = 0; mt < 2; ++mt) {
            int r = m0 + mt * 16 + sub;
            int rc = r < NN ? r : NN - 1;
            const float* hp = hsrc + (size_t)rc * H + kb;
            float4 v0 = *(const float4*)hp;
            float4 v1 = *(const float4*)(hp + 4);
            float vv[8] = {v0.x, v0.y, v0.z, v0.w, v1.x, v1.y, v1.z, v1.w};
            if (applyBN) {
#pragma unroll
                for (int i = 0; i < 8; ++i) {
                    float v = fmaf(vv[i], sc8[i], sh8[i]);
                    vv[i] = v > 0.0f ? v : 0.0f;
                }
            }
            bf8_t hi8, lo8;
#pragma unroll
            for (int i = 0; i < 8; ++i) {
                ushort_t hi = f2bf(vv[i]);
                hi8[i] = (short)hi;
                lo8[i] = (short)f2bf(vv[i] - bf2f(hi));
            }
            aHi[mt][ks] = hi8;
            aLo[mt][ks] = lo8;
            if (writeH && r < NN) {
                float* op = hbn + (size_t)r * H + kb;
                *(float4*)op = make_float4(vv[0], vv[1], vv[2], vv[3]);
                *(float4*)(op + 4) = make_float4(vv[4], vv[5], vv[6], vv[7]);
            }
        }
    }
    __syncthreads();

    f4_t acc[2][8];
#pragma unroll
    for (int a = 0; a < 2; ++a)
#pragma unroll
        for (int b = 0; b < 8; ++b) acc[a][b] = (f4_t){0.f, 0.f, 0.f, 0.f};

#pragma unroll
    for (int nt = 0; nt < 8; ++nt) {
#pragma unroll
        for (int ks = 0; ks < 4; ++ks) {
            size_t lo = ((size_t)(nt * 16 + sub) * BPAD + ks * 4 + quad) * 8;
            bf8_t bHi = *(const bf8_t*)(lbHi + lo);
            bf8_t bLo = *(const bf8_t*)(lbLo + lo);
#pragma unroll
            for (int mt = 0; mt < 2; ++mt) {
                acc[mt][nt] = __builtin_amdgcn_mfma_f32_16x16x32_bf16(aHi[mt][ks], bHi, acc[mt][nt], 0, 0, 0);
                acc[mt][nt] = __builtin_amdgcn_mfma_f32_16x16x32_bf16(aLo[mt][ks], bHi, acc[mt][nt], 0, 0, 0);
                acc[mt][nt] = __builtin_amdgcn_mfma_f32_16x16x32_bf16(aHi[mt][ks], bLo, acc[mt][nt], 0, 0, 0);
            }
        }
    }

    float* outp = (table == 0) ? tab0 : (table == 1) ? tab1 : (table == 2) ? tab2 : tab3;
#pragma unroll
    for (int mt = 0; mt < 2; ++mt)
#pragma unroll
        for (int nt = 0; nt < 8; ++nt) {
            int col = nt * 16 + sub;
#pragma unroll
            for (int rr = 0; rr < 4; ++rr) {
                int row = m0 + mt * 16 + quad * 4 + rr;
                if (row < NN) outp[(size_t)row * H + col] = acc[mt][nt][rr];
            }
        }
}

// Edge-parallel segmented CSR aggregation with precomputed segment metadata:
// endmask bit t = "position t ends its segment"; csr_inv = invdeg[dst[t]].
// No scan loops, no indexed invdeg loads — boundary logic is mask bit-tests
// + ctz; flush values all come from registers.
__global__ __launch_bounds__(256) void agg_edge_kernel(const int4* __restrict__ csr_fe,
                                                       const int* __restrict__ csr_dst,
                                                       const float* __restrict__ csr_inv,
                                                       const unsigned* __restrict__ endmask,
                                                       const float* __restrict__ Wf,
                                                       const float* __restrict__ bf,
                                                       const float* __restrict__ Ws,
                                                       const float* __restrict__ bs,
                                                       const float* __restrict__ tab0,
                                                       const float* __restrict__ tab1,
                                                       const float* __restrict__ tab2,
                                                       const float* __restrict__ tab3,
                                                       float* __restrict__ h,
                                                       float* __restrict__ sum,
                                                       float* __restrict__ sumsq) {
    int tid = threadIdx.x;
    if (blockIdx.x == 0 && tid < H) { sum[tid] = 0.0f; sumsq[tid] = 0.0f; }
    int lane = tid & 63;
    int wv = tid >> 6;
    int base = (blockIdx.x * 4 + wv) * EPW;
    int c0 = 2 * lane;

    const float2* Pf2 = (const float2*)tab0;
    const float2* Ps2 = (const float2*)tab1;
    const float2* Qf2 = (const float2*)tab2;
    const float2* Qs2 = (const float2*)tab3;

    float2 wf0 = *(const float2*)&Wf[256 * H + c0];
    float2 wf1 = *(const float2*)&Wf[257 * H + c0];
    float2 wf2 = *(const float2*)&Wf[258 * H + c0];
    float2 ws0 = *(const float2*)&Ws[256 * H + c0];
    float2 ws1 = *(const float2*)&Ws[257 * H + c0];
    float2 ws2 = *(const float2*)&Ws[258 * H + c0];
    float2 bf2_ = *(const float2*)&bf[c0];
    float2 bs2_ = *(const float2*)&bs[c0];

    // lanes replicate 16 edge records 4x (broadcast reads)
    int4 fe = csr_fe[base + (lane & (EPW - 1))];
    int  dd = csr_dst[base + (lane & (EPW - 1))];
    int  ivr = __float_as_int(csr_inv[base + (lane & (EPW - 1))]);
    unsigned mword = endmask[base >> 5];
    unsigned mask = __builtin_amdgcn_readfirstlane((mword >> (base & 31)) & 0xFFFFu);

    float2 qf[8], qs[8];
#pragma unroll
    for (int i = 0; i < 8; ++i) {
        int s = __builtin_amdgcn_readlane(fe.w, i);
        qf[i] = Qf2[(size_t)s * 64 + lane];
        qs[i] = Qs2[(size_t)s * 64 + lane];
    }

    int dcur = __builtin_amdgcn_readlane(dd, 0);
    float2 pfCur = Pf2[(size_t)dcur * 64 + lane];
    float2 psCur = Ps2[(size_t)dcur * 64 + lane];
    unsigned m = mask;
    int e0 = m ? __builtin_ctz(m) : EPW;   // end of current segment
    int dnext = 0;
    float2 pfN = pfCur, psN = psCur;
    if (e0 + 1 < EPW) {
        dnext = __builtin_amdgcn_readlane(dd, e0 + 1);
        pfN = Pf2[(size_t)dnext * 64 + lane];
        psN = Ps2[(size_t)dnext * 64 + lane];
    }

    float acc0 = 0.f, acc1 = 0.f;

#pragma unroll
    for (int tb = 0; tb < EPW; tb += 8) {
#pragma unroll
        for (int i = 0; i < 8; ++i) {
            int t = tb + i;
            float ex = __int_as_float(__builtin_amdgcn_readlane(fe.x, t));
            float ey = __int_as_float(__builtin_amdgcn_readlane(fe.y, t));
            float ez = __int_as_float(__builtin_amdgcn_readlane(fe.z, t));
            float2 qqf = qf[i], qqs = qs[i];
            if (t + 8 < EPW) {
                int s2 = __builtin_amdgcn_readlane(fe.w, t + 8);
                qf[i] = Qf2[(size_t)s2 * 64 + lane];
                qs[i] = Qs2[(size_t)s2 * 64 + lane];
            }
            float f0 = fmaf(ex, wf0.x, fmaf(ey, wf1.x, fmaf(ez, wf2.x, pfCur.x + bf2_.x + qqf.x)));
            float v0 = fmaf(ex, ws0.x, fmaf(ey, ws1.x, fmaf(ez, ws2.x, psCur.x + bs2_.x + qqs.x)));
            float f1 = fmaf(ex, wf0.y, fmaf(ey, wf1.y, fmaf(ez, wf2.y, pfCur.y + bf2_.y + qqf.y)));
            float v1 = fmaf(ex, ws0.y, fmaf(ey, ws1.y, fmaf(ez, ws2.y, psCur.y + bs2_.y + qqs.y)));
            float sig0 = __builtin_amdgcn_rcpf(1.0f + __expf(-f0));
            float sp0  = fmaxf(v0, 0.0f) + __logf(1.0f + __expf(-fabsf(v0)));
            float sig1 = __builtin_amdgcn_rcpf(1.0f + __expf(-f1));
            float sp1  = fmaxf(v1, 0.0f) + __logf(1.0f + __expf(-fabsf(v1)));
            acc0 = fmaf(sig0, sp0, acc0);
            acc1 = fmaf(sig1, sp1, acc1);
            if (mask & (1u << t)) {   // wave-uniform segment end (precomputed)
                float inv = __int_as_float(__builtin_amdgcn_readlane(ivr, t));
                atomicAdd(&h[(size_t)dcur * H + c0], acc0 * inv);
                atomicAdd(&h[(size_t)dcur * H + c0 + 1], acc1 * inv);
                acc0 = 0.f; acc1 = 0.f;
                dcur = dnext;
                pfCur = pfN;
                psCur = psN;
                m &= m - 1;
                int e1 = m ? __builtin_ctz(m) : EPW;   // end of (new) current segment
                if (e1 + 1 < EPW) {
                    dnext = __builtin_amdgcn_readlane(dd, e1 + 1);
                    pfN = Pf2[(size_t)dnext * 64 + lane];
                    psN = Ps2[(size_t)dnext * 64 + lane];
                }
            }
        }
    }
    if (!(mask & (1u << (EPW - 1)))) {   // trailing partial segment
        float inv = __int_as_float(__builtin_amdgcn_readlane(ivr, EPW - 1));
        atomicAdd(&h[(size_t)dcur * H + c0], acc0 * inv);
        atomicAdd(&h[(size_t)dcur * H + c0 + 1], acc1 * inv);
    }
}

// per-column sum / sumsq; 4 independent row loads per iteration.
__global__ __launch_bounds__(H) void stats_kernel(const float* __restrict__ h,
                                                  float* __restrict__ sum,
                                                  float* __restrict__ sumsq) {
    int j = threadIdx.x;
    float s = 0.0f, ss = 0.0f;
    int n = blockIdx.x * 4;
    for (; n + 3 < NN; n += gridDim.x * 4) {
        float v0 = h[(size_t)(n + 0) * H + j];
        float v1 = h[(size_t)(n + 1) * H + j];
        float v2 = h[(size_t)(n + 2) * H + j];
        float v3 = h[(size_t)(n + 3) * H + j];
        s += (v0 + v1) + (v2 + v3);
        ss = fmaf(v0, v0, ss); ss = fmaf(v1, v1, ss);
        ss = fmaf(v2, v2, ss); ss = fmaf(v3, v3, ss);
    }
    for (; n < NN; ++n) {
        float v = h[(size_t)n * H + j];
        s += v;
        ss = fmaf(v, v, ss);
    }
    atomicAdd(&sum[j], s);
    atomicAdd(&sumsq[j], ss);
}

__global__ __launch_bounds__(H) void pool_kernel(const float* __restrict__ h,
                                                 const int* __restrict__ batch,
                                                 const float* __restrict__ sum,
                                                 const float* __restrict__ sumsq,
                                                 const float* __restrict__ gamma,
                                                 const float* __restrict__ beta,
                                                 float* __restrict__ g,
                                                 float* __restrict__ cnt) {
    int j = threadIdx.x;
    float mu  = sum[j] * (1.0f / NN);
    float var = sumsq[j] * (1.0f / NN) - mu * mu;
    float sc  = gamma[j] * rsqrtf(var + BN_EPSF);
    float sh  = beta[j] - mu * sc;
    for (int n = blockIdx.x; n < NN; n += gridDim.x) {
        int b = batch[n];
        float v = fmaf(h[(size_t)n * H + j], sc, sh);
        v = v > 0.0f ? v : 0.0f;
        atomicAdd(&g[(size_t)b * H + j], v);
        if (j == 0) atomicAdd(&cnt[b], 1.0f);
    }
}

__global__ __launch_bounds__(H) void mlp_kernel(const float* __restrict__ g,
                                                const float* __restrict__ cnt,
                                                const float* __restrict__ W1,
                                                const float* __restrict__ b1,
                                                const float* __restrict__ W2,
                                                const float* __restrict__ b2,
                                                const float* __restrict__ W3,
                                                const float* __restrict__ b3,
                                                float* __restrict__ out) {
    int gid = blockIdx.x, j = threadIdx.x;
    __shared__ float s1[H];
    __shared__ float s2[H];
    __shared__ float wsum[2];
    float c = cnt[gid];
    c = c < 1.0f ? 1.0f : c;
    s1[j] = g[gid * H + j] / c;
    __syncthreads();
    float a = b1[j];
    for (int k = 0; k < H; ++k) a = fmaf(s1[k], W1[k * H + j], a);
    a = a > 0.0f ? a : 0.0f;
    s2[j] = a;
    __syncthreads();
    float t = b2[j];
    for (int k = 0; k < H; ++k) t = fmaf(s2[k], W2[k * H + j], t);
    t = t > 0.0f ? t : 0.0f;
    float p = t * W3[j];
    for (int off = 32; off > 0; off >>= 1) p += __shfl_down(p, off, 64);
    if ((j & 63) == 0) wsum[j >> 6] = p;
    __syncthreads();
    if (j == 0) out[gid] = wsum[0] + wsum[1] + b3[0];
}

extern "C" void kernel_launch(void* const* d_in, const int* in_sizes, int n_in,
                              void* d_out, int out_size, void* d_ws, size_t ws_size,
                              hipStream_t stream) {
    const float* x     = (const float*)d_in[0];
    const int*   ei    = (const int*)d_in[1];
    const int*   srcp  = ei;        // edge_index[0] = source (x_j)
    const int*   dstp  = ei + NE;   // edge_index[1] = target (aggregation index)
    const int*   batch = (const int*)d_in[2];
    const float* ea    = (const float*)d_in[3];
    const float* Win   = (const float*)d_in[4];
    const float* bin   = (const float*)d_in[5];
    const float* Wf    = (const float*)d_in[6];
    const float* bf    = (const float*)d_in[7];
    const float* Ws    = (const float*)d_in[8];
    const float* bs    = (const float*)d_in[9];
    const float* gamma = (const float*)d_in[10];
    const float* beta  = (const float*)d_in[11];
    const float* W1    = (const float*)d_in[12];
    const float* b1    = (const float*)d_in[13];
    const float* W2    = (const float*)d_in[14];
    const float* b2    = (const float*)d_in[15];
    const float* W3    = (const float*)d_in[16];
    const float* b3    = (const float*)d_in[17];
    float* out = (float*)d_out;

    const size_t NH = (size_t)NN * H;
    float* wsp = (float*)d_ws;
    size_t off = 0;
    float* hA     = wsp + off; off += NH;
    float* hB     = wsp + off; off += NH;
    float* tab0   = wsp + off; off += NH;   // Pf
    float* tab1   = wsp + off; off += NH;   // Ps
    float* tab2   = wsp + off; off += NH;   // Qf
    float* tab3   = wsp + off; off += NH;   // Qs
    float* invdeg = wsp + off; off += NN;
    float* sum    = wsp + off; off += H;
    float* sumsq  = wsp + off; off += H;
    float* g      = wsp + off; off += (size_t)NG * H;
    float* cnt    = wsp + off; off += NG;
    off = (off + 3) & ~(size_t)3;
    float4* csr_ea4 = (float4*)(wsp + off); off += (size_t)NE * 4;
    float* csr_inv = wsp + off; off += NE;
    int* degi      = (int*)(wsp + off); off += NN;
    int* counter   = (int*)(wsp + off); off += 1;
    unsigned* endmask = (unsigned*)(wsp + off); off += NE / 32;
    int* cursor    = (int*)(wsp + off); off += NN;
    int* csr_dst   = (int*)(wsp + off); off += NE;
    off = (off + 3) & ~(size_t)3;
    ushort_t* Wt_hi = (ushort_t*)(wsp + off); off += (size_t)NL * 512 * H / 2;
    ushort_t* Wt_lo = (ushort_t*)(wsp + off); off += (size_t)NL * 512 * H / 2;

    // ---- CSR + weight prep (topology/weights fixed across layers) ----
    // zero degi + counter + endmask in one memset (contiguous)
    hipMemsetAsync(degi, 0, (NN + 1 + NE / 32) * sizeof(int), stream);
    deg_int_kernel<<<(NE + 255) / 256, 256, 0, stream>>>(dstp, degi);
    reserve_kernel<<<(NN + 255) / 256, 256, 0, stream>>>(degi, cursor, invdeg, counter);
    scatter_kernel<<<(NE + 255) / 256, 256, 0, stream>>>(srcp, dstp, ea, invdeg, cursor,
                                                         csr_ea4, csr_dst, csr_inv);
    flag_kernel<<<(NE + 255) / 256, 256, 0, stream>>>(csr_dst, endmask);
    wprep_kernel<<<(NL * 512 * H + 255) / 256, 256, 0, stream>>>(Wf, Ws, Wt_hi, Wt_lo);

    hin_kernel<<<NN, H, 0, stream>>>(x, Win, bin, hA);

    float* hRead = hA;
    for (int l = 0; l < NL; ++l) {
        float* hTgt = (l == 0) ? hA : ((l & 1) ? hB : hA);
        node_gemm_mfma<<<dim3((NN + 127) / 128, 4), 256, 0, stream>>>(
            hRead, hTgt,
            Wt_hi + (size_t)l * 512 * H,
            Wt_lo + (size_t)l * 512 * H,
            sum, sumsq,
            gamma + (size_t)(l ? l - 1 : 0) * H,
            beta  + (size_t)(l ? l - 1 : 0) * H,
            l > 0, tab0, tab1, tab2, tab3);
        agg_edge_kernel<<<NE / (4 * EPW), 256, 0, stream>>>((const int4*)csr_ea4, csr_dst,
                                                            csr_inv, endmask,
                                                            Wf + (size_t)l * ZDH, bf + (size_t)l * H,
                                                            Ws + (size_t)l * ZDH, bs + (size_t)l * H,
                                                            tab0, tab1, tab2, tab3,
                                                            hTgt, sum, sumsq);
        stats_kernel<<<512, H, 0, stream>>>(hTgt, sum, sumsq);
        hRead = hTgt;
    }

    hipMemsetAsync(g, 0, ((size_t)NG * H + NG) * sizeof(float), stream);
    pool_kernel<<<2048, H, 0, stream>>>(hRead, batch, sum, sumsq,
                                        gamma + (size_t)(NL - 1) * H,
                                        beta + (size_t)(NL - 1) * H, g, cnt);
    mlp_kernel<<<NG, H, 0, stream>>>(g, cnt, W1, b1, W2, b2, W3, b3, out);
}

// Round 15
// 544.316 us; speedup vs baseline: 1.0029x; 1.0029x over previous
//
#include <hip/hip_runtime.h>
#include <math.h>

#define NN 20000
#define NE 160000
#define NG 1000
#define IND 11
#define H 128
#define ED 3
#define NL 5
#define ZDH (259*128)
#define BN_EPSF 1e-5f
#define BPAD 17   /* 16B-chunks per B-row in LDS (16 + 1 pad) */
#define EPW 16    /* edges per wave in agg_edge */

typedef unsigned short ushort_t;
typedef unsigned int uint_t;
typedef __attribute__((ext_vector_type(8))) short bf8_t;
typedef __attribute__((ext_vector_type(4))) float f4_t;

__device__ inline ushort_t f2bf(float x) {
    unsigned int u = __float_as_uint(x);
    unsigned int r = (u + 0x7fffu + ((u >> 16) & 1u)) >> 16;
    return (ushort_t)r;
}
__device__ inline float bf2f(ushort_t b) {
    return __uint_as_float(((unsigned int)b) << 16);
}

// ---------------- CSR build (once per call) ----------------

__global__ void deg_int_kernel(const int* __restrict__ dst, int* __restrict__ degi) {
    int e = blockIdx.x * blockDim.x + threadIdx.x;
    if (e < NE) atomicAdd(&degi[dst[e]], 1);
}

__global__ __launch_bounds__(256) void reserve_kernel(const int* __restrict__ degi,
                                                      int* __restrict__ cursor,
                                                      float* __restrict__ invdeg,
                                                      int* __restrict__ counter) {
    int n = blockIdx.x * blockDim.x + threadIdx.x;
    int lane = threadIdx.x & 63;
    int v = (n < NN) ? degi[n] : 0;
    int x = v;
#pragma unroll
    for (int st = 1; st < 64; st <<= 1) {
        int y = __shfl_up(x, st, 64);
        if (lane >= st) x += y;
    }
    int total = __shfl(x, 63, 64);
    int base = 0;
    if (lane == 63) base = atomicAdd(counter, total);
    base = __shfl(base, 63, 64);
    if (n < NN) {
        cursor[n] = base + x - v;
        invdeg[n] = 1.0f / (float)(v < 1 ? 1 : v);
    }
}

__global__ void scatter_kernel(const int* __restrict__ src, const int* __restrict__ dst,
                               const float* __restrict__ ea,
                               const float* __restrict__ invdeg,
                               int* __restrict__ cursor, float4* __restrict__ csr_ea4,
                               int* __restrict__ csr_dst, float* __restrict__ csr_inv) {
    int e = blockIdx.x * blockDim.x + threadIdx.x;
    if (e < NE) {
        int d = dst[e];
        int pos = atomicAdd(&cursor[d], 1);
        float4 r;
        r.x = ea[e * ED + 0];
        r.y = ea[e * ED + 1];
        r.z = ea[e * ED + 2];
        r.w = __int_as_float(src[e]);
        csr_ea4[pos] = r;
        csr_dst[pos] = d;
        csr_inv[pos] = invdeg[d];
    }
}

// marks the last CSR position of each dst-segment in a bitmask
__global__ void flag_kernel(const int* __restrict__ csr_dst, unsigned* __restrict__ endmask) {
    int e = blockIdx.x * blockDim.x + threadIdx.x;
    if (e < NE) {
        int d = csr_dst[e];
        int dn = (e + 1 < NE) ? csr_dst[e + 1] : -1;
        if (d != dn) atomicOr(&endmask[e >> 5], 1u << (e & 31));
    }
}

// ---------------- weight prep: transpose to [n][k] bf16 hi/lo ----------------
// table order: 0=Pf(Wf k<128), 1=Ps(Ws k<128), 2=Qf(Wf k>=128), 3=Qs(Ws k>=128)
__global__ void wprep_kernel(const float* __restrict__ Wf, const float* __restrict__ Ws,
                             ushort_t* __restrict__ Wt_hi, ushort_t* __restrict__ Wt_lo) {
    int idx = blockIdx.x * 256 + threadIdx.x;   // l*65536 + n*128 + k
    if (idx >= NL * 512 * H) return;
    int k = idx & 127;
    int n = (idx >> 7) & 511;
    int l = idx >> 16;
    int t = n >> 7, j = n & 127;
    const float* W = (t == 0 || t == 2) ? Wf : Ws;
    int krow = (t < 2) ? k : (H + k);
    float v = W[(size_t)l * ZDH + krow * H + j];
    ushort_t hi = f2bf(v);
    Wt_hi[idx] = hi;
    Wt_lo[idx] = f2bf(v - bf2f(hi));
}

// ---------------- network ----------------

__global__ __launch_bounds__(H) void hin_kernel(const float* __restrict__ x,
                                                const float* __restrict__ Win,
                                                const float* __restrict__ bin,
                                                float* __restrict__ h) {
    int n = blockIdx.x;
    int j = threadIdx.x;
    __shared__ float xr[IND];
    if (j < IND) xr[j] = x[n * IND + j];
    __syncthreads();
    float acc = bin[j];
#pragma unroll
    for (int k = 0; k < IND; ++k) acc = fmaf(xr[k], Win[k * H + j], acc);
    h[(size_t)n * H + j] = acc;
}

// MFMA node GEMM v5 (unchanged from R12): B staged in LDS once per block.
__global__ __launch_bounds__(256, 2) void node_gemm_mfma(const float* __restrict__ hsrc,
                                                         float* __restrict__ hbn,
                                                         const ushort_t* __restrict__ Wt_hi,
                                                         const ushort_t* __restrict__ Wt_lo,
                                                         const float* __restrict__ sum,
                                                         const float* __restrict__ sumsq,
                                                         const float* __restrict__ gamma,
                                                         const float* __restrict__ beta,
                                                         int applyBN,
                                                         float* __restrict__ tab0,
                                                         float* __restrict__ tab1,
                                                         float* __restrict__ tab2,
                                                         float* __restrict__ tab3) {
    __shared__ __align__(16) ushort_t lbHi[128 * BPAD * 8];
    __shared__ __align__(16) ushort_t lbLo[128 * BPAD * 8];
    int table = blockIdx.y;
    int wave = threadIdx.x >> 6;
    int lane = threadIdx.x & 63;
    int sub = lane & 15;
    int quad = lane >> 4;
    int m0 = blockIdx.x * 128 + wave * 32;
    int writeH = applyBN && (table == 0);

    const ushort_t* wh = Wt_hi + (size_t)table * 128 * H;
    const ushort_t* wl = Wt_lo + (size_t)table * 128 * H;

    for (int c = threadIdx.x; c < 2048; c += 256) {
        int n = c >> 4, k = c & 15;
        bf8_t vh = *(const bf8_t*)(wh + n * H + k * 8);
        bf8_t vl = *(const bf8_t*)(wl + n * H + k * 8);
        *(bf8_t*)(lbHi + ((size_t)n * BPAD + k) * 8) = vh;
        *(bf8_t*)(lbLo + ((size_t)n * BPAD + k) * 8) = vl;
    }

    bf8_t aHi[2][4], aLo[2][4];
#pragma unroll
    for (int ks = 0; ks < 4; ++ks) {
        int kb = ks * 32 + quad * 8;
        float sc8[8], sh8[8];
        if (applyBN) {
            float4 su0 = *(const float4*)&sum[kb],   su1 = *(const float4*)&sum[kb + 4];
            float4 sq0 = *(const float4*)&sumsq[kb], sq1 = *(const float4*)&sumsq[kb + 4];
            float4 ga0 = *(const float4*)&gamma[kb], ga1 = *(const float4*)&gamma[kb + 4];
            float4 be0 = *(const float4*)&beta[kb],  be1 = *(const float4*)&beta[kb + 4];
            float su[8] = {su0.x, su0.y, su0.z, su0.w, su1.x, su1.y, su1.z, su1.w};
            float sq[8] = {sq0.x, sq0.y, sq0.z, sq0.w, sq1.x, sq1.y, sq1.z, sq1.w};
            float ga[8] = {ga0.x, ga0.y, ga0.z, ga0.w, ga1.x, ga1.y, ga1.z, ga1.w};
            float be[8] = {be0.x, be0.y, be0.z, be0.w, be1.x, be1.y, be1.z, be1.w};
#pragma unroll
            for (int i = 0; i < 8; ++i) {
                float mu  = su[i] * (1.0f / NN);
                float var = sq[i] * (1.0f / NN) - mu * mu;
                sc8[i] = ga[i] * rsqrtf(var + BN_EPSF);
                sh8[i] = be[i] - mu * sc8[i];
            }
        }
#pragma unroll
        for (int mt = 0; mt < 2; ++mt) {
            int r = m0 + mt * 16 + sub;
            int rc = r < NN ? r : NN - 1;
            const float* hp = hsrc + (size_t)rc * H + kb;
            float4 v0 = *(const float4*)hp;
            float4 v1 = *(const float4*)(hp + 4);
            float vv[8] = {v0.x, v0.y, v0.z, v0.w, v1.x, v1.y, v1.z, v1.w};
            if (applyBN) {
#pragma unroll
                for (int i = 0; i < 8; ++i) {
                    float v = fmaf(vv[i], sc8[i], sh8[i]);
                    vv[i] = v > 0.0f ? v : 0.0f;
                }
            }
            bf8_t hi8, lo8;
#pragma unroll
            for (int i = 0; i < 8; ++i) {
                ushort_t hi = f2bf(vv[i]);
                hi8[i] = (short)hi;
                lo8[i] = (short)f2bf(vv[i] - bf2f(hi));
            }
            aHi[mt][ks] = hi8;
            aLo[mt][ks] = lo8;
            if (writeH && r < NN) {
                float* op = hbn + (size_t)r * H + kb;
                *(float4*)op = make_float4(vv[0], vv[1], vv[2], vv[3]);
                *(float4*)(op + 4) = make_float4(vv[4], vv[5], vv[6], vv[7]);
            }
        }
    }
    __syncthreads();

    f4_t acc[2][8];
#pragma unroll
    for (int a = 0; a < 2; ++a)
#pragma unroll
        for (int b = 0; b < 8; ++b) acc[a][b] = (f4_t){0.f, 0.f, 0.f, 0.f};

#pragma unroll
    for (int nt = 0; nt < 8; ++nt) {
#pragma unroll
        for (int ks = 0; ks < 4; ++ks) {
            size_t lo = ((size_t)(nt * 16 + sub) * BPAD + ks * 4 + quad) * 8;
            bf8_t bHi = *(const bf8_t*)(lbHi + lo);
            bf8_t bLo = *(const bf8_t*)(lbLo + lo);
#pragma unroll
            for (int mt = 0; mt < 2; ++mt) {
                acc[mt][nt] = __builtin_amdgcn_mfma_f32_16x16x32_bf16(aHi[mt][ks], bHi, acc[mt][nt], 0, 0, 0);
                acc[mt][nt] = __builtin_amdgcn_mfma_f32_16x16x32_bf16(aLo[mt][ks], bHi, acc[mt][nt], 0, 0, 0);
                acc[mt][nt] = __builtin_amdgcn_mfma_f32_16x16x32_bf16(aHi[mt][ks], bLo, acc[mt][nt], 0, 0, 0);
            }
        }
    }

    float* outp = (table == 0) ? tab0 : (table == 1) ? tab1 : (table == 2) ? tab2 : tab3;
#pragma unroll
    for (int mt = 0; mt < 2; ++mt)
#pragma unroll
        for (int nt = 0; nt < 8; ++nt) {
            int col = nt * 16 + sub;
#pragma unroll
            for (int rr = 0; rr < 4; ++rr) {
                int row = m0 + mt * 16 + quad * 4 + rr;
                if (row < NN) outp[(size_t)row * H + col] = acc[mt][nt][rr];
            }
        }
}

// Packs Qf/Qs fp32 planar tables into one uint per (n,j):
// low16 = bf16(Qf), high16 = bf16(Qs). Halves agg's per-edge gather bytes.
__global__ __launch_bounds__(256) void pack_q_kernel(const float* __restrict__ tab2,
                                                     const float* __restrict__ tab3,
                                                     uint_t* __restrict__ qpack) {
    int idx = blockIdx.x * 256 + threadIdx.x;
    if (idx < NN * H) {
        uint_t lo = f2bf(tab2[idx]);
        uint_t hi = f2bf(tab3[idx]);
        qpack[idx] = lo | (hi << 16);
    }
}

// Edge-parallel segmented CSR aggregation; Q gathered as packed bf16 pairs
// (one uint2 per lane per edge — half the bytes of the fp32 split tables).
// Pf/Ps per-segment loads stay fp32. Segment metadata precomputed (endmask,
// csr_inv).
__global__ __launch_bounds__(256) void agg_edge_kernel(const int4* __restrict__ csr_fe,
                                                       const int* __restrict__ csr_dst,
                                                       const float* __restrict__ csr_inv,
                                                       const unsigned* __restrict__ endmask,
                                                       const float* __restrict__ Wf,
                                                       const float* __restrict__ bf,
                                                       const float* __restrict__ Ws,
                                                       const float* __restrict__ bs,
                                                       const float* __restrict__ tab0,
                                                       const float* __restrict__ tab1,
                                                       const uint_t* __restrict__ qpack,
                                                       float* __restrict__ h,
                                                       float* __restrict__ sum,
                                                       float* __restrict__ sumsq) {
    int tid = threadIdx.x;
    if (blockIdx.x == 0 && tid < H) { sum[tid] = 0.0f; sumsq[tid] = 0.0f; }
    int lane = tid & 63;
    int wv = tid >> 6;
    int base = (blockIdx.x * 4 + wv) * EPW;
    int c0 = 2 * lane;

    const float2* Pf2 = (const float2*)tab0;
    const float2* Ps2 = (const float2*)tab1;

    float2 wf0 = *(const float2*)&Wf[256 * H + c0];
    float2 wf1 = *(const float2*)&Wf[257 * H + c0];
    float2 wf2 = *(const float2*)&Wf[258 * H + c0];
    float2 ws0 = *(const float2*)&Ws[256 * H + c0];
    float2 ws1 = *(const float2*)&Ws[257 * H + c0];
    float2 ws2 = *(const float2*)&Ws[258 * H + c0];
    float2 bf2_ = *(const float2*)&bf[c0];
    float2 bs2_ = *(const float2*)&bs[c0];

    // lanes replicate 16 edge records 4x (broadcast reads)
    int4 fe = csr_fe[base + (lane & (EPW - 1))];
    int  dd = csr_dst[base + (lane & (EPW - 1))];
    int  ivr = __float_as_int(csr_inv[base + (lane & (EPW - 1))]);
    unsigned mword = endmask[base >> 5];
    unsigned mask = __builtin_amdgcn_readfirstlane((mword >> (base & 31)) & 0xFFFFu);

    uint2 q[8];
#pragma unroll
    for (int i = 0; i < 8; ++i) {
        int s = __builtin_amdgcn_readlane(fe.w, i);
        q[i] = *(const uint2*)&qpack[(size_t)s * H + c0];
    }

    int dcur = __builtin_amdgcn_readlane(dd, 0);
    float2 pfCur = Pf2[(size_t)dcur * 64 + lane];
    float2 psCur = Ps2[(size_t)dcur * 64 + lane];
    unsigned m = mask;
    int e0 = m ? __builtin_ctz(m) : EPW;
    int dnext = 0;
    float2 pfN = pfCur, psN = psCur;
    if (e0 + 1 < EPW) {
        dnext = __builtin_amdgcn_readlane(dd, e0 + 1);
        pfN = Pf2[(size_t)dnext * 64 + lane];
        psN = Ps2[(size_t)dnext * 64 + lane];
    }

    float acc0 = 0.f, acc1 = 0.f;

#pragma unroll
    for (int tb = 0; tb < EPW; tb += 8) {
#pragma unroll
        for (int i = 0; i < 8; ++i) {
            int t = tb + i;
            float ex = __int_as_float(__builtin_amdgcn_readlane(fe.x, t));
            float ey = __int_as_float(__builtin_amdgcn_readlane(fe.y, t));
            float ez = __int_as_float(__builtin_amdgcn_readlane(fe.z, t));
            uint2 qq = q[i];
            if (t + 8 < EPW) {
                int s2 = __builtin_amdgcn_readlane(fe.w, t + 8);
                q[i] = *(const uint2*)&qpack[(size_t)s2 * H + c0];
            }
            float qf0 = __uint_as_float(qq.x << 16);
            float qs0 = __uint_as_float(qq.x & 0xFFFF0000u);
            float qf1 = __uint_as_float(qq.y << 16);
            float qs1 = __uint_as_float(qq.y & 0xFFFF0000u);
            float f0 = fmaf(ex, wf0.x, fmaf(ey, wf1.x, fmaf(ez, wf2.x, pfCur.x + bf2_.x + qf0)));
            float v0 = fmaf(ex, ws0.x, fmaf(ey, ws1.x, fmaf(ez, ws2.x, psCur.x + bs2_.x + qs0)));
            float f1 = fmaf(ex, wf0.y, fmaf(ey, wf1.y, fmaf(ez, wf2.y, pfCur.y + bf2_.y + qf1)));
            float v1 = fmaf(ex, ws0.y, fmaf(ey, ws1.y, fmaf(ez, ws2.y, psCur.y + bs2_.y + qs1)));
            float sig0 = __builtin_amdgcn_rcpf(1.0f + __expf(-f0));
            float sp0  = fmaxf(v0, 0.0f) + __logf(1.0f + __expf(-fabsf(v0)));
            float sig1 = __builtin_amdgcn_rcpf(1.0f + __expf(-f1));
            float sp1  = fmaxf(v1, 0.0f) + __logf(1.0f + __expf(-fabsf(v1)));
            acc0 = fmaf(sig0, sp0, acc0);
            acc1 = fmaf(sig1, sp1, acc1);
            if (mask & (1u << t)) {   // wave-uniform segment end (precomputed)
                float inv = __int_as_float(__builtin_amdgcn_readlane(ivr, t));
                atomicAdd(&h[(size_t)dcur * H + c0], acc0 * inv);
                atomicAdd(&h[(size_t)dcur * H + c0 + 1], acc1 * inv);
                acc0 = 0.f; acc1 = 0.f;
                dcur = dnext;
                pfCur = pfN;
                psCur = psN;
                m &= m - 1;
                int e1 = m ? __builtin_ctz(m) : EPW;
                if (e1 + 1 < EPW) {
                    dnext = __builtin_amdgcn_readlane(dd, e1 + 1);
                    pfN = Pf2[(size_t)dnext * 64 + lane];
                    psN = Ps2[(size_t)dnext * 64 + lane];
                }
            }
        }
    }
    if (!(mask & (1u << (EPW - 1)))) {   // trailing partial segment
        float inv = __int_as_float(__builtin_amdgcn_readlane(ivr, EPW - 1));
        atomicAdd(&h[(size_t)dcur * H + c0], acc0 * inv);
        atomicAdd(&h[(size_t)dcur * H + c0 + 1], acc1 * inv);
    }
}

// per-column sum / sumsq; 8 independent row loads per iteration.
__global__ __launch_bounds__(H) void stats_kernel(const float* __restrict__ h,
                                                  float* __restrict__ sum,
                                                  float* __restrict__ sumsq) {
    int j = threadIdx.x;
    float s = 0.0f, ss = 0.0f;
    int n = blockIdx.x * 8;
    for (; n + 7 < NN; n += gridDim.x * 8) {
        float v[8];
#pragma unroll
        for (int i = 0; i < 8; ++i) v[i] = h[(size_t)(n + i) * H + j];
#pragma unroll
        for (int i = 0; i < 8; ++i) { s += v[i]; ss = fmaf(v[i], v[i], ss); }
    }
    for (; n < NN; ++n) {
        float v = h[(size_t)n * H + j];
        s += v;
        ss = fmaf(v, v, ss);
    }
    atomicAdd(&sum[j], s);
    atomicAdd(&sumsq[j], ss);
}

__global__ __launch_bounds__(H) void pool_kernel(const float* __restrict__ h,
                                                 const int* __restrict__ batch,
                                                 const float* __restrict__ sum,
                                                 const float* __restrict__ sumsq,
                                                 const float* __restrict__ gamma,
                                                 const float* __restrict__ beta,
                                                 float* __restrict__ g,
                                                 float* __restrict__ cnt) {
    int j = threadIdx.x;
    float mu  = sum[j] * (1.0f / NN);
    float var = sumsq[j] * (1.0f / NN) - mu * mu;
    float sc  = gamma[j] * rsqrtf(var + BN_EPSF);
    float sh  = beta[j] - mu * sc;
    for (int n = blockIdx.x; n < NN; n += gridDim.x) {
        int b = batch[n];
        float v = fmaf(h[(size_t)n * H + j], sc, sh);
        v = v > 0.0f ? v : 0.0f;
        atomicAdd(&g[(size_t)b * H + j], v);
        if (j == 0) atomicAdd(&cnt[b], 1.0f);
    }
}

__global__ __launch_bounds__(H) void mlp_kernel(const float* __restrict__ g,
                                                const float* __restrict__ cnt,
                                                const float* __restrict__ W1,
                                                const float* __restrict__ b1,
                                                const float* __restrict__ W2,
                                                const float* __restrict__ b2,
                                                const float* __restrict__ W3,
                                                const float* __restrict__ b3,
                                                float* __restrict__ out) {
    int gid = blockIdx.x, j = threadIdx.x;
    __shared__ float s1[H];
    __shared__ float s2[H];
    __shared__ float wsum[2];
    float c = cnt[gid];
    c = c < 1.0f ? 1.0f : c;
    s1[j] = g[gid * H + j] / c;
    __syncthreads();
    float a = b1[j];
    for (int k = 0; k < H; ++k) a = fmaf(s1[k], W1[k * H + j], a);
    a = a > 0.0f ? a : 0.0f;
    s2[j] = a;
    __syncthreads();
    float t = b2[j];
    for (int k = 0; k < H; ++k) t = fmaf(s2[k], W2[k * H + j], t);
    t = t > 0.0f ? t : 0.0f;
    float p = t * W3[j];
    for (int off = 32; off > 0; off >>= 1) p += __shfl_down(p, off, 64);
    if ((j & 63) == 0) wsum[j >> 6] = p;
    __syncthreads();
    if (j == 0) out[gid] = wsum[0] + wsum[1] + b3[0];
}

extern "C" void kernel_launch(void* const* d_in, const int* in_sizes, int n_in,
                              void* d_out, int out_size, void* d_ws, size_t ws_size,
                              hipStream_t stream) {
    const float* x     = (const float*)d_in[0];
    const int*   ei    = (const int*)d_in[1];
    const int*   srcp  = ei;        // edge_index[0] = source (x_j)
    const int*   dstp  = ei + NE;   // edge_index[1] = target (aggregation index)
    const int*   batch = (const int*)d_in[2];
    const float* ea    = (const float*)d_in[3];
    const float* Win   = (const float*)d_in[4];
    const float* bin   = (const float*)d_in[5];
    const float* Wf    = (const float*)d_in[6];
    const float* bf    = (const float*)d_in[7];
    const float* Ws    = (const float*)d_in[8];
    const float* bs    = (const float*)d_in[9];
    const float* gamma = (const float*)d_in[10];
    const float* beta  = (const float*)d_in[11];
    const float* W1    = (const float*)d_in[12];
    const float* b1    = (const float*)d_in[13];
    const float* W2    = (const float*)d_in[14];
    const float* b2    = (const float*)d_in[15];
    const float* W3    = (const float*)d_in[16];
    const float* b3    = (const float*)d_in[17];
    float* out = (float*)d_out;

    const size_t NH = (size_t)NN * H;
    float* wsp = (float*)d_ws;
    size_t off = 0;
    float* hA     = wsp + off; off += NH;
    float* hB     = wsp + off; off += NH;
    float* tab0   = wsp + off; off += NH;   // Pf
    float* tab1   = wsp + off; off += NH;   // Ps
    float* tab2   = wsp + off; off += NH;   // Qf
    float* tab3   = wsp + off; off += NH;   // Qs
    uint_t* qpack = (uint_t*)(wsp + off); off += NH;  // packed bf16 (Qf,Qs)
    float* invdeg = wsp + off; off += NN;
    float* sum    = wsp + off; off += H;
    float* sumsq  = wsp + off; off += H;
    float* g      = wsp + off; off += (size_t)NG * H;
    float* cnt    = wsp + off; off += NG;
    off = (off + 3) & ~(size_t)3;
    float4* csr_ea4 = (float4*)(wsp + off); off += (size_t)NE * 4;
    float* csr_inv = wsp + off; off += NE;
    int* degi      = (int*)(wsp + off); off += NN;
    int* counter   = (int*)(wsp + off); off += 1;
    unsigned* endmask = (unsigned*)(wsp + off); off += NE / 32;
    int* cursor    = (int*)(wsp + off); off += NN;
    int* csr_dst   = (int*)(wsp + off); off += NE;
    off = (off + 3) & ~(size_t)3;
    ushort_t* Wt_hi = (ushort_t*)(wsp + off); off += (size_t)NL * 512 * H / 2;
    ushort_t* Wt_lo = (ushort_t*)(wsp + off); off += (size_t)NL * 512 * H / 2;

    // ---- CSR + weight prep (topology/weights fixed across layers) ----
    // zero degi + counter + endmask in one memset (contiguous)
    hipMemsetAsync(degi, 0, (NN + 1 + NE / 32) * sizeof(int), stream);
    deg_int_kernel<<<(NE + 255) / 256, 256, 0, stream>>>(dstp, degi);
    reserve_kernel<<<(NN + 255) / 256, 256, 0, stream>>>(degi, cursor, invdeg, counter);
    scatter_kernel<<<(NE + 255) / 256, 256, 0, stream>>>(srcp, dstp, ea, invdeg, cursor,
                                                         csr_ea4, csr_dst, csr_inv);
    flag_kernel<<<(NE + 255) / 256, 256, 0, stream>>>(csr_dst, endmask);
    wprep_kernel<<<(NL * 512 * H + 255) / 256, 256, 0, stream>>>(Wf, Ws, Wt_hi, Wt_lo);

    hin_kernel<<<NN, H, 0, stream>>>(x, Win, bin, hA);

    float* hRead = hA;
    for (int l = 0; l < NL; ++l) {
        float* hTgt = (l == 0) ? hA : ((l & 1) ? hB : hA);
        node_gemm_mfma<<<dim3((NN + 127) / 128, 4), 256, 0, stream>>>(
            hRead, hTgt,
            Wt_hi + (size_t)l * 512 * H,
            Wt_lo + (size_t)l * 512 * H,
            sum, sumsq,
            gamma + (size_t)(l ? l - 1 : 0) * H,
            beta  + (size_t)(l ? l - 1 : 0) * H,
            l > 0, tab0, tab1, tab2, tab3);
        pack_q_kernel<<<(NN * H + 255) / 256, 256, 0, stream>>>(tab2, tab3, qpack);
        agg_edge_kernel<<<NE / (4 * EPW), 256, 0, stream>>>((const int4*)csr_ea4, csr_dst,
                                                            csr_inv, endmask,
                                                            Wf + (size_t)l * ZDH, bf + (size_t)l * H,
                                                            Ws + (size_t)l * ZDH, bs + (size_t)l * H,
                                                            tab0, tab1, qpack,
                                                            hTgt, sum, sumsq);
        stats_kernel<<<512, H, 0, stream>>>(hTgt, sum, sumsq);
        hRead = hTgt;
    }

    hipMemsetAsync(g, 0, ((size_t)NG * H + NG) * sizeof(float), stream);
    pool_kernel<<<2048, H, 0, stream>>>(hRead, batch, sum, sumsq,
                                        gamma + (size_t)(NL - 1) * H,
                                        beta + (size_t)(NL - 1) * H, g, cnt);
    mlp_kernel<<<NG, H, 0, stream>>>(g, cnt, W1, b1, W2, b2, W3, b3, out);
}

// Round 16
// 528.062 us; speedup vs baseline: 1.0338x; 1.0308x over previous
//
#include <hip/hip_runtime.h>
#include <math.h>

#define NN 20000
#define NE 160000
#define NG 1000
#define IND 11
#define H 128
#define ED 3
#define NL 5
#define ZDH (259*128)
#define BN_EPSF 1e-5f
#define BPAD 17   /* 16B-chunks per B-row in LDS (16 + 1 pad) */
#define EPW 16    /* edges per wave in agg_edge */

typedef unsigned short ushort_t;
typedef unsigned int uint_t;
typedef __attribute__((ext_vector_type(8))) short bf8_t;
typedef __attribute__((ext_vector_type(4))) float f4_t;

__device__ inline ushort_t f2bf(float x) {
    unsigned int u = __float_as_uint(x);
    unsigned int r = (u + 0x7fffu + ((u >> 16) & 1u)) >> 16;
    return (ushort_t)r;
}
__device__ inline float bf2f(ushort_t b) {
    return __uint_as_float(((unsigned int)b) << 16);
}

// ---------------- CSR build (once per call) ----------------

__global__ void deg_int_kernel(const int* __restrict__ dst, int* __restrict__ degi) {
    int e = blockIdx.x * blockDim.x + threadIdx.x;
    if (e < NE) atomicAdd(&degi[dst[e]], 1);
}

__global__ __launch_bounds__(256) void reserve_kernel(const int* __restrict__ degi,
                                                      int* __restrict__ cursor,
                                                      float* __restrict__ invdeg,
                                                      int* __restrict__ counter) {
    int n = blockIdx.x * blockDim.x + threadIdx.x;
    int lane = threadIdx.x & 63;
    int v = (n < NN) ? degi[n] : 0;
    int x = v;
#pragma unroll
    for (int st = 1; st < 64; st <<= 1) {
        int y = __shfl_up(x, st, 64);
        if (lane >= st) x += y;
    }
    int total = __shfl(x, 63, 64);
    int base = 0;
    if (lane == 63) base = atomicAdd(counter, total);
    base = __shfl(base, 63, 64);
    if (n < NN) {
        cursor[n] = base + x - v;
        invdeg[n] = 1.0f / (float)(v < 1 ? 1 : v);
    }
}

__global__ void scatter_kernel(const int* __restrict__ src, const int* __restrict__ dst,
                               const float* __restrict__ ea,
                               const float* __restrict__ invdeg,
                               int* __restrict__ cursor, float4* __restrict__ csr_ea4,
                               int* __restrict__ csr_dst, float* __restrict__ csr_inv) {
    int e = blockIdx.x * blockDim.x + threadIdx.x;
    if (e < NE) {
        int d = dst[e];
        int pos = atomicAdd(&cursor[d], 1);
        float4 r;
        r.x = ea[e * ED + 0];
        r.y = ea[e * ED + 1];
        r.z = ea[e * ED + 2];
        r.w = __int_as_float(src[e]);
        csr_ea4[pos] = r;
        csr_dst[pos] = d;
        csr_inv[pos] = invdeg[d];
    }
}

// marks the last CSR position of each dst-segment in a bitmask
__global__ void flag_kernel(const int* __restrict__ csr_dst, unsigned* __restrict__ endmask) {
    int e = blockIdx.x * blockDim.x + threadIdx.x;
    if (e < NE) {
        int d = csr_dst[e];
        int dn = (e + 1 < NE) ? csr_dst[e + 1] : -1;
        if (d != dn) atomicOr(&endmask[e >> 5], 1u << (e & 31));
    }
}

// ---------------- weight prep: transpose to [n][k] bf16 hi/lo ----------------
// table order: 0=Pf(Wf k<128), 1=Ps(Ws k<128), 2=Qf(Wf k>=128), 3=Qs(Ws k>=128)
__global__ void wprep_kernel(const float* __restrict__ Wf, const float* __restrict__ Ws,
                             ushort_t* __restrict__ Wt_hi, ushort_t* __restrict__ Wt_lo) {
    int idx = blockIdx.x * 256 + threadIdx.x;   // l*65536 + n*128 + k
    if (idx >= NL * 512 * H) return;
    int k = idx & 127;
    int n = (idx >> 7) & 511;
    int l = idx >> 16;
    int t = n >> 7, j = n & 127;
    const float* W = (t == 0 || t == 2) ? Wf : Ws;
    int krow = (t < 2) ? k : (H + k);
    float v = W[(size_t)l * ZDH + krow * H + j];
    ushort_t hi = f2bf(v);
    Wt_hi[idx] = hi;
    Wt_lo[idx] = f2bf(v - bf2f(hi));
}

// ---------------- network ----------------

__global__ __launch_bounds__(H) void hin_kernel(const float* __restrict__ x,
                                                const float* __restrict__ Win,
                                                const float* __restrict__ bin,
                                                float* __restrict__ h) {
    int n = blockIdx.x;
    int j = threadIdx.x;
    __shared__ float xr[IND];
    if (j < IND) xr[j] = x[n * IND + j];
    __syncthreads();
    float acc = bin[j];
#pragma unroll
    for (int k = 0; k < IND; ++k) acc = fmaf(xr[k], Win[k * H + j], acc);
    h[(size_t)n * H + j] = acc;
}

// MFMA node GEMM v6: B in LDS (R12); epilogue packs outputs directly to bf16
// halves of ppack/qpack (byte-disjoint ushort stores across tables — no race:
// table 0/2 write low halves (Pf/Qf), table 1/3 high halves (Ps/Qs)).
// Eliminates the separate pack kernel and the fp32 planar tables.
__global__ __launch_bounds__(256, 2) void node_gemm_mfma(const float* __restrict__ hsrc,
                                                         float* __restrict__ hbn,
                                                         const ushort_t* __restrict__ Wt_hi,
                                                         const ushort_t* __restrict__ Wt_lo,
                                                         const float* __restrict__ sum,
                                                         const float* __restrict__ sumsq,
                                                         const float* __restrict__ gamma,
                                                         const float* __restrict__ beta,
                                                         int applyBN,
                                                         uint_t* __restrict__ ppack,
                                                         uint_t* __restrict__ qpack) {
    __shared__ __align__(16) ushort_t lbHi[128 * BPAD * 8];
    __shared__ __align__(16) ushort_t lbLo[128 * BPAD * 8];
    int table = blockIdx.y;
    int wave = threadIdx.x >> 6;
    int lane = threadIdx.x & 63;
    int sub = lane & 15;
    int quad = lane >> 4;
    int m0 = blockIdx.x * 128 + wave * 32;
    int writeH = applyBN && (table == 0);

    const ushort_t* wh = Wt_hi + (size_t)table * 128 * H;
    const ushort_t* wl = Wt_lo + (size_t)table * 128 * H;

    for (int c = threadIdx.x; c < 2048; c += 256) {
        int n = c >> 4, k = c & 15;
        bf8_t vh = *(const bf8_t*)(wh + n * H + k * 8);
        bf8_t vl = *(const bf8_t*)(wl + n * H + k * 8);
        *(bf8_t*)(lbHi + ((size_t)n * BPAD + k) * 8) = vh;
        *(bf8_t*)(lbLo + ((size_t)n * BPAD + k) * 8) = vl;
    }

    bf8_t aHi[2][4], aLo[2][4];
#pragma unroll
    for (int ks = 0; ks < 4; ++ks) {
        int kb = ks * 32 + quad * 8;
        float sc8[8], sh8[8];
        if (applyBN) {
            float4 su0 = *(const float4*)&sum[kb],   su1 = *(const float4*)&sum[kb + 4];
            float4 sq0 = *(const float4*)&sumsq[kb], sq1 = *(const float4*)&sumsq[kb + 4];
            float4 ga0 = *(const float4*)&gamma[kb], ga1 = *(const float4*)&gamma[kb + 4];
            float4 be0 = *(const float4*)&beta[kb],  be1 = *(const float4*)&beta[kb + 4];
            float su[8] = {su0.x, su0.y, su0.z, su0.w, su1.x, su1.y, su1.z, su1.w};
            float sq[8] = {sq0.x, sq0.y, sq0.z, sq0.w, sq1.x, sq1.y, sq1.z, sq1.w};
            float ga[8] = {ga0.x, ga0.y, ga0.z, ga0.w, ga1.x, ga1.y, ga1.z, ga1.w};
            float be[8] = {be0.x, be0.y, be0.z, be0.w, be1.x, be1.y, be1.z, be1.w};
#pragma unroll
            for (int i = 0; i < 8; ++i) {
                float mu  = su[i] * (1.0f / NN);
                float var = sq[i] * (1.0f / NN) - mu * mu;
                sc8[i] = ga[i] * rsqrtf(var + BN_EPSF);
                sh8[i] = be[i] - mu * sc8[i];
            }
        }
#pragma unroll
        for (int mt = 0; mt < 2; ++mt) {
            int r = m0 + mt * 16 + sub;
            int rc = r < NN ? r : NN - 1;
            const float* hp = hsrc + (size_t)rc * H + kb;
            float4 v0 = *(const float4*)hp;
            float4 v1 = *(const float4*)(hp + 4);
            float vv[8] = {v0.x, v0.y, v0.z, v0.w, v1.x, v1.y, v1.z, v1.w};
            if (applyBN) {
#pragma unroll
                for (int i = 0; i < 8; ++i) {
                    float v = fmaf(vv[i], sc8[i], sh8[i]);
                    vv[i] = v > 0.0f ? v : 0.0f;
                }
            }
            bf8_t hi8, lo8;
#pragma unroll
            for (int i = 0; i < 8; ++i) {
                ushort_t hi = f2bf(vv[i]);
                hi8[i] = (short)hi;
                lo8[i] = (short)f2bf(vv[i] - bf2f(hi));
            }
            aHi[mt][ks] = hi8;
            aLo[mt][ks] = lo8;
            if (writeH && r < NN) {
                float* op = hbn + (size_t)r * H + kb;
                *(float4*)op = make_float4(vv[0], vv[1], vv[2], vv[3]);
                *(float4*)(op + 4) = make_float4(vv[4], vv[5], vv[6], vv[7]);
            }
        }
    }
    __syncthreads();

    f4_t acc[2][8];
#pragma unroll
    for (int a = 0; a < 2; ++a)
#pragma unroll
        for (int b = 0; b < 8; ++b) acc[a][b] = (f4_t){0.f, 0.f, 0.f, 0.f};

#pragma unroll
    for (int nt = 0; nt < 8; ++nt) {
#pragma unroll
        for (int ks = 0; ks < 4; ++ks) {
            size_t lo = ((size_t)(nt * 16 + sub) * BPAD + ks * 4 + quad) * 8;
            bf8_t bHi = *(const bf8_t*)(lbHi + lo);
            bf8_t bLo = *(const bf8_t*)(lbLo + lo);
#pragma unroll
            for (int mt = 0; mt < 2; ++mt) {
                acc[mt][nt] = __builtin_amdgcn_mfma_f32_16x16x32_bf16(aHi[mt][ks], bHi, acc[mt][nt], 0, 0, 0);
                acc[mt][nt] = __builtin_amdgcn_mfma_f32_16x16x32_bf16(aLo[mt][ks], bHi, acc[mt][nt], 0, 0, 0);
                acc[mt][nt] = __builtin_amdgcn_mfma_f32_16x16x32_bf16(aHi[mt][ks], bLo, acc[mt][nt], 0, 0, 0);
            }
        }
    }

    // bf16 pack epilogue: table 0/1 -> ppack low/high halves, 2/3 -> qpack.
    ushort_t* outp = (ushort_t*)((table < 2) ? ppack : qpack);
    int par = table & 1;
#pragma unroll
    for (int mt = 0; mt < 2; ++mt)
#pragma unroll
        for (int nt = 0; nt < 8; ++nt) {
            int col = nt * 16 + sub;
#pragma unroll
            for (int rr = 0; rr < 4; ++rr) {
                int row = m0 + mt * 16 + quad * 4 + rr;
                if (row < NN) outp[2 * ((size_t)row * H + col) + par] = f2bf(acc[mt][nt][rr]);
            }
        }
}

// Edge-parallel segmented CSR aggregation; P and Q both gathered as packed
// bf16 pairs (uint2 per lane). Segment metadata precomputed (endmask, csr_inv).
__global__ __launch_bounds__(256) void agg_edge_kernel(const int4* __restrict__ csr_fe,
                                                       const int* __restrict__ csr_dst,
                                                       const float* __restrict__ csr_inv,
                                                       const unsigned* __restrict__ endmask,
                                                       const float* __restrict__ Wf,
                                                       const float* __restrict__ bf,
                                                       const float* __restrict__ Ws,
                                                       const float* __restrict__ bs,
                                                       const uint_t* __restrict__ ppack,
                                                       const uint_t* __restrict__ qpack,
                                                       float* __restrict__ h,
                                                       float* __restrict__ sum,
                                                       float* __restrict__ sumsq) {
    int tid = threadIdx.x;
    if (blockIdx.x == 0 && tid < H) { sum[tid] = 0.0f; sumsq[tid] = 0.0f; }
    int lane = tid & 63;
    int wv = tid >> 6;
    int base = (blockIdx.x * 4 + wv) * EPW;
    int c0 = 2 * lane;

    float2 wf0 = *(const float2*)&Wf[256 * H + c0];
    float2 wf1 = *(const float2*)&Wf[257 * H + c0];
    float2 wf2 = *(const float2*)&Wf[258 * H + c0];
    float2 ws0 = *(const float2*)&Ws[256 * H + c0];
    float2 ws1 = *(const float2*)&Ws[257 * H + c0];
    float2 ws2 = *(const float2*)&Ws[258 * H + c0];
    float2 bf2_ = *(const float2*)&bf[c0];
    float2 bs2_ = *(const float2*)&bs[c0];

    // lanes replicate 16 edge records 4x (broadcast reads)
    int4 fe = csr_fe[base + (lane & (EPW - 1))];
    int  dd = csr_dst[base + (lane & (EPW - 1))];
    int  ivr = __float_as_int(csr_inv[base + (lane & (EPW - 1))]);
    unsigned mword = endmask[base >> 5];
    unsigned mask = __builtin_amdgcn_readfirstlane((mword >> (base & 31)) & 0xFFFFu);

    uint2 q[8];
#pragma unroll
    for (int i = 0; i < 8; ++i) {
        int s = __builtin_amdgcn_readlane(fe.w, i);
        q[i] = *(const uint2*)&qpack[(size_t)s * H + c0];
    }

    int dcur = __builtin_amdgcn_readlane(dd, 0);
    uint2 ppc = *(const uint2*)&ppack[(size_t)dcur * H + c0];
    float pf0 = __uint_as_float(ppc.x << 16), ps0 = __uint_as_float(ppc.x & 0xFFFF0000u);
    float pf1 = __uint_as_float(ppc.y << 16), ps1 = __uint_as_float(ppc.y & 0xFFFF0000u);
    unsigned m = mask;
    int e0 = m ? __builtin_ctz(m) : EPW;
    int dnext = 0;
    uint2 ppN = ppc;
    if (e0 + 1 < EPW) {
        dnext = __builtin_amdgcn_readlane(dd, e0 + 1);
        ppN = *(const uint2*)&ppack[(size_t)dnext * H + c0];
    }

    float acc0 = 0.f, acc1 = 0.f;

#pragma unroll
    for (int tb = 0; tb < EPW; tb += 8) {
#pragma unroll
        for (int i = 0; i < 8; ++i) {
            int t = tb + i;
            float ex = __int_as_float(__builtin_amdgcn_readlane(fe.x, t));
            float ey = __int_as_float(__builtin_amdgcn_readlane(fe.y, t));
            float ez = __int_as_float(__builtin_amdgcn_readlane(fe.z, t));
            uint2 qq = q[i];
            if (t + 8 < EPW) {
                int s2 = __builtin_amdgcn_readlane(fe.w, t + 8);
                q[i] = *(const uint2*)&qpack[(size_t)s2 * H + c0];
            }
            float qf0 = __uint_as_float(qq.x << 16);
            float qs0 = __uint_as_float(qq.x & 0xFFFF0000u);
            float qf1 = __uint_as_float(qq.y << 16);
            float qs1 = __uint_as_float(qq.y & 0xFFFF0000u);
            float f0 = fmaf(ex, wf0.x, fmaf(ey, wf1.x, fmaf(ez, wf2.x, pf0 + bf2_.x + qf0)));
            float v0 = fmaf(ex, ws0.x, fmaf(ey, ws1.x, fmaf(ez, ws2.x, ps0 + bs2_.x + qs0)));
            float f1 = fmaf(ex, wf0.y, fmaf(ey, wf1.y, fmaf(ez, wf2.y, pf1 + bf2_.y + qf1)));
            float v1 = fmaf(ex, ws0.y, fmaf(ey, ws1.y, fmaf(ez, ws2.y, ps1 + bs2_.y + qs1)));
            float sig0 = __builtin_amdgcn_rcpf(1.0f + __expf(-f0));
            float sp0  = fmaxf(v0, 0.0f) + __logf(1.0f + __expf(-fabsf(v0)));
            float sig1 = __builtin_amdgcn_rcpf(1.0f + __expf(-f1));
            float sp1  = fmaxf(v1, 0.0f) + __logf(1.0f + __expf(-fabsf(v1)));
            acc0 = fmaf(sig0, sp0, acc0);
            acc1 = fmaf(sig1, sp1, acc1);
            if (mask & (1u << t)) {   // wave-uniform segment end (precomputed)
                float inv = __int_as_float(__builtin_amdgcn_readlane(ivr, t));
                atomicAdd(&h[(size_t)dcur * H + c0], acc0 * inv);
                atomicAdd(&h[(size_t)dcur * H + c0 + 1], acc1 * inv);
                acc0 = 0.f; acc1 = 0.f;
                dcur = dnext;
                pf0 = __uint_as_float(ppN.x << 16); ps0 = __uint_as_float(ppN.x & 0xFFFF0000u);
                pf1 = __uint_as_float(ppN.y << 16); ps1 = __uint_as_float(ppN.y & 0xFFFF0000u);
                m &= m - 1;
                int e1 = m ? __builtin_ctz(m) : EPW;
                if (e1 + 1 < EPW) {
                    dnext = __builtin_amdgcn_readlane(dd, e1 + 1);
                    ppN = *(const uint2*)&ppack[(size_t)dnext * H + c0];
                }
            }
        }
    }
    if (!(mask & (1u << (EPW - 1)))) {   // trailing partial segment
        float inv = __int_as_float(__builtin_amdgcn_readlane(ivr, EPW - 1));
        atomicAdd(&h[(size_t)dcur * H + c0], acc0 * inv);
        atomicAdd(&h[(size_t)dcur * H + c0 + 1], acc1 * inv);
    }
}

// per-column sum / sumsq; 8 independent row loads per iteration.
__global__ __launch_bounds__(H) void stats_kernel(const float* __restrict__ h,
                                                  float* __restrict__ sum,
                                                  float* __restrict__ sumsq) {
    int j = threadIdx.x;
    float s = 0.0f, ss = 0.0f;
    int n = blockIdx.x * 8;
    for (; n + 7 < NN; n += gridDim.x * 8) {
        float v[8];
#pragma unroll
        for (int i = 0; i < 8; ++i) v[i] = h[(size_t)(n + i) * H + j];
#pragma unroll
        for (int i = 0; i < 8; ++i) { s += v[i]; ss = fmaf(v[i], v[i], ss); }
    }
    for (; n < NN; ++n) {
        float v = h[(size_t)n * H + j];
        s += v;
        ss = fmaf(v, v, ss);
    }
    atomicAdd(&sum[j], s);
    atomicAdd(&sumsq[j], ss);
}

__global__ __launch_bounds__(H) void pool_kernel(const float* __restrict__ h,
                                                 const int* __restrict__ batch,
                                                 const float* __restrict__ sum,
                                                 const float* __restrict__ sumsq,
                                                 const float* __restrict__ gamma,
                                                 const float* __restrict__ beta,
                                                 float* __restrict__ g,
                                                 float* __restrict__ cnt) {
    int j = threadIdx.x;
    float mu  = sum[j] * (1.0f / NN);
    float var = sumsq[j] * (1.0f / NN) - mu * mu;
    float sc  = gamma[j] * rsqrtf(var + BN_EPSF);
    float sh  = beta[j] - mu * sc;
    for (int n = blockIdx.x; n < NN; n += gridDim.x) {
        int b = batch[n];
        float v = fmaf(h[(size_t)n * H + j], sc, sh);
        v = v > 0.0f ? v : 0.0f;
        atomicAdd(&g[(size_t)b * H + j], v);
        if (j == 0) atomicAdd(&cnt[b], 1.0f);
    }
}

__global__ __launch_bounds__(H) void mlp_kernel(const float* __restrict__ g,
                                                const float* __restrict__ cnt,
                                                const float* __restrict__ W1,
                                                const float* __restrict__ b1,
                                                const float* __restrict__ W2,
                                                const float* __restrict__ b2,
                                                const float* __restrict__ W3,
                                                const float* __restrict__ b3,
                                                float* __restrict__ out) {
    int gid = blockIdx.x, j = threadIdx.x;
    __shared__ float s1[H];
    __shared__ float s2[H];
    __shared__ float wsum[2];
    float c = cnt[gid];
    c = c < 1.0f ? 1.0f : c;
    s1[j] = g[gid * H + j] / c;
    __syncthreads();
    float a = b1[j];
    for (int k = 0; k < H; ++k) a = fmaf(s1[k], W1[k * H + j], a);
    a = a > 0.0f ? a : 0.0f;
    s2[j] = a;
    __syncthreads();
    float t = b2[j];
    for (int k = 0; k < H; ++k) t = fmaf(s2[k], W2[k * H + j], t);
    t = t > 0.0f ? t : 0.0f;
    float p = t * W3[j];
    for (int off = 32; off > 0; off >>= 1) p += __shfl_down(p, off, 64);
    if ((j & 63) == 0) wsum[j >> 6] = p;
    __syncthreads();
    if (j == 0) out[gid] = wsum[0] + wsum[1] + b3[0];
}

extern "C" void kernel_launch(void* const* d_in, const int* in_sizes, int n_in,
                              void* d_out, int out_size, void* d_ws, size_t ws_size,
                              hipStream_t stream) {
    const float* x     = (const float*)d_in[0];
    const int*   ei    = (const int*)d_in[1];
    const int*   srcp  = ei;        // edge_index[0] = source (x_j)
    const int*   dstp  = ei + NE;   // edge_index[1] = target (aggregation index)
    const int*   batch = (const int*)d_in[2];
    const float* ea    = (const float*)d_in[3];
    const float* Win   = (const float*)d_in[4];
    const float* bin   = (const float*)d_in[5];
    const float* Wf    = (const float*)d_in[6];
    const float* bf    = (const float*)d_in[7];
    const float* Ws    = (const float*)d_in[8];
    const float* bs    = (const float*)d_in[9];
    const float* gamma = (const float*)d_in[10];
    const float* beta  = (const float*)d_in[11];
    const float* W1    = (const float*)d_in[12];
    const float* b1    = (const float*)d_in[13];
    const float* W2    = (const float*)d_in[14];
    const float* b2    = (const float*)d_in[15];
    const float* W3    = (const float*)d_in[16];
    const float* b3    = (const float*)d_in[17];
    float* out = (float*)d_out;

    const size_t NH = (size_t)NN * H;
    float* wsp = (float*)d_ws;
    size_t off = 0;
    float* hA     = wsp + off; off += NH;
    float* hB     = wsp + off; off += NH;
    uint_t* ppack = (uint_t*)(wsp + off); off += NH;  // packed bf16 (Pf,Ps)
    uint_t* qpack = (uint_t*)(wsp + off); off += NH;  // packed bf16 (Qf,Qs)
    float* invdeg = wsp + off; off += NN;
    float* sum    = wsp + off; off += H;
    float* sumsq  = wsp + off; off += H;
    float* g      = wsp + off; off += (size_t)NG * H;
    float* cnt    = wsp + off; off += NG;
    off = (off + 3) & ~(size_t)3;
    float4* csr_ea4 = (float4*)(wsp + off); off += (size_t)NE * 4;
    float* csr_inv = wsp + off; off += NE;
    int* degi      = (int*)(wsp + off); off += NN;
    int* counter   = (int*)(wsp + off); off += 1;
    unsigned* endmask = (unsigned*)(wsp + off); off += NE / 32;
    int* cursor    = (int*)(wsp + off); off += NN;
    int* csr_dst   = (int*)(wsp + off); off += NE;
    off = (off + 3) & ~(size_t)3;
    ushort_t* Wt_hi = (ushort_t*)(wsp + off); off += (size_t)NL * 512 * H / 2;
    ushort_t* Wt_lo = (ushort_t*)(wsp + off); off += (size_t)NL * 512 * H / 2;

    // ---- CSR + weight prep (topology/weights fixed across layers) ----
    // zero degi + counter + endmask in one memset (contiguous)
    hipMemsetAsync(degi, 0, (NN + 1 + NE / 32) * sizeof(int), stream);
    deg_int_kernel<<<(NE + 255) / 256, 256, 0, stream>>>(dstp, degi);
    reserve_kernel<<<(NN + 255) / 256, 256, 0, stream>>>(degi, cursor, invdeg, counter);
    scatter_kernel<<<(NE + 255) / 256, 256, 0, stream>>>(srcp, dstp, ea, invdeg, cursor,
                                                         csr_ea4, csr_dst, csr_inv);
    flag_kernel<<<(NE + 255) / 256, 256, 0, stream>>>(csr_dst, endmask);
    wprep_kernel<<<(NL * 512 * H + 255) / 256, 256, 0, stream>>>(Wf, Ws, Wt_hi, Wt_lo);

    hin_kernel<<<NN, H, 0, stream>>>(x, Win, bin, hA);

    float* hRead = hA;
    for (int l = 0; l < NL; ++l) {
        float* hTgt = (l == 0) ? hA : ((l & 1) ? hB : hA);
        node_gemm_mfma<<<dim3((NN + 127) / 128, 4), 256, 0, stream>>>(
            hRead, hTgt,
            Wt_hi + (size_t)l * 512 * H,
            Wt_lo + (size_t)l * 512 * H,
            sum, sumsq,
            gamma + (size_t)(l ? l - 1 : 0) * H,
            beta  + (size_t)(l ? l - 1 : 0) * H,
            l > 0, ppack, qpack);
        agg_edge_kernel<<<NE / (4 * EPW), 256, 0, stream>>>((const int4*)csr_ea4, csr_dst,
                                                            csr_inv, endmask,
                                                            Wf + (size_t)l * ZDH, bf + (size_t)l * H,
                                                            Ws + (size_t)l * ZDH, bs + (size_t)l * H,
                                                            ppack, qpack,
                                                            hTgt, sum, sumsq);
        stats_kernel<<<512, H, 0, stream>>>(hTgt, sum, sumsq);
        hRead = hTgt;
    }

    hipMemsetAsync(g, 0, ((size_t)NG * H + NG) * sizeof(float), stream);
    pool_kernel<<<2048, H, 0, stream>>>(hRead, batch, sum, sumsq,
                                        gamma + (size_t)(NL - 1) * H,
                                        beta + (size_t)(NL - 1) * H, g, cnt);
    mlp_kernel<<<NG, H, 0, stream>>>(g, cnt, W1, b1, W2, b2, W3, b3, out);
}

// Round 17
// 491.315 us; speedup vs baseline: 1.1111x; 1.0748x over previous
//
#include <hip/hip_runtime.h>
#include <math.h>

#define NN 20000
#define NE 160000
#define NG 1000
#define IND 11
#define H 128
#define ED 3
#define NL 5
#define ZDH (259*128)
#define BN_EPSF 1e-5f
#define BPAD 17   /* 16B-chunks per B-row in LDS (16 + 1 pad) */
#define EPW 16    /* edges per wave in agg_edge */

typedef unsigned short ushort_t;
typedef unsigned int uint_t;
typedef __attribute__((ext_vector_type(8))) short bf8_t;
typedef __attribute__((ext_vector_type(4))) float f4_t;

__device__ inline ushort_t f2bf(float x) {
    unsigned int u = __float_as_uint(x);
    unsigned int r = (u + 0x7fffu + ((u >> 16) & 1u)) >> 16;
    return (ushort_t)r;
}
__device__ inline float bf2f(ushort_t b) {
    return __uint_as_float(((unsigned int)b) << 16);
}

// ---------------- CSR build (once per call) ----------------

__global__ void deg_int_kernel(const int* __restrict__ dst, int* __restrict__ degi) {
    int e = blockIdx.x * blockDim.x + threadIdx.x;
    if (e < NE) atomicAdd(&degi[dst[e]], 1);
}

__global__ __launch_bounds__(256) void reserve_kernel(const int* __restrict__ degi,
                                                      int* __restrict__ cursor,
                                                      float* __restrict__ invdeg,
                                                      int* __restrict__ counter) {
    int n = blockIdx.x * blockDim.x + threadIdx.x;
    int lane = threadIdx.x & 63;
    int v = (n < NN) ? degi[n] : 0;
    int x = v;
#pragma unroll
    for (int st = 1; st < 64; st <<= 1) {
        int y = __shfl_up(x, st, 64);
        if (lane >= st) x += y;
    }
    int total = __shfl(x, 63, 64);
    int base = 0;
    if (lane == 63) base = atomicAdd(counter, total);
    base = __shfl(base, 63, 64);
    if (n < NN) {
        cursor[n] = base + x - v;
        invdeg[n] = 1.0f / (float)(v < 1 ? 1 : v);
    }
}

__global__ void scatter_kernel(const int* __restrict__ src, const int* __restrict__ dst,
                               const float* __restrict__ ea,
                               const float* __restrict__ invdeg,
                               int* __restrict__ cursor, float4* __restrict__ csr_ea4,
                               int* __restrict__ csr_dst, float* __restrict__ csr_inv) {
    int e = blockIdx.x * blockDim.x + threadIdx.x;
    if (e < NE) {
        int d = dst[e];
        int pos = atomicAdd(&cursor[d], 1);
        float4 r;
        r.x = ea[e * ED + 0];
        r.y = ea[e * ED + 1];
        r.z = ea[e * ED + 2];
        r.w = __int_as_float(src[e]);
        csr_ea4[pos] = r;
        csr_dst[pos] = d;
        csr_inv[pos] = invdeg[d];
    }
}

// marks the last CSR position of each dst-segment in a bitmask
__global__ void flag_kernel(const int* __restrict__ csr_dst, unsigned* __restrict__ endmask) {
    int e = blockIdx.x * blockDim.x + threadIdx.x;
    if (e < NE) {
        int d = csr_dst[e];
        int dn = (e + 1 < NE) ? csr_dst[e + 1] : -1;
        if (d != dn) atomicOr(&endmask[e >> 5], 1u << (e & 31));
    }
}

// ---------------- weight prep: transpose to [n][k] bf16 ----------------
// table order: 0=Pf(Wf k<128), 1=Ps(Ws k<128), 2=Qf(Wf k>=128), 3=Qs(Ws k>=128)
__global__ void wprep_kernel(const float* __restrict__ Wf, const float* __restrict__ Ws,
                             ushort_t* __restrict__ Wt) {
    int idx = blockIdx.x * 256 + threadIdx.x;   // l*65536 + n*128 + k
    if (idx >= NL * 512 * H) return;
    int k = idx & 127;
    int n = (idx >> 7) & 511;
    int l = idx >> 16;
    int t = n >> 7, j = n & 127;
    const float* W = (t == 0 || t == 2) ? Wf : Ws;
    int krow = (t < 2) ? k : (H + k);
    Wt[idx] = f2bf(W[(size_t)l * ZDH + krow * H + j]);
}

// ---------------- network ----------------

__global__ __launch_bounds__(H) void hin_kernel(const float* __restrict__ x,
                                                const float* __restrict__ Win,
                                                const float* __restrict__ bin,
                                                float* __restrict__ h) {
    int n = blockIdx.x;
    int j = threadIdx.x;
    __shared__ float xr[IND];
    if (j < IND) xr[j] = x[n * IND + j];
    __syncthreads();
    float acc = bin[j];
#pragma unroll
    for (int k = 0; k < IND; ++k) acc = fmaf(xr[k], Win[k * H + j], acc);
    h[(size_t)n * H + j] = acc;
}

// MFMA node GEMM v7: grid (ceil(NN/64), 2). y=0 computes (Pf,Ps)->ppack,
// y=1 (Qf,Qs)->qpack — one thread owns both output halves, so stores are
// full coalesced uints (no byte-split write amplification). B is plain bf16
// in LDS (two tables fit in 68 KB); A keeps the hi/lo split (A exact, only
// B quantized). Wave owns 16 rows. Fused BN on A path; y=0 writes hbn.
__global__ __launch_bounds__(256, 2) void node_gemm_mfma(const float* __restrict__ hsrc,
                                                         float* __restrict__ hbn,
                                                         const ushort_t* __restrict__ Wt,
                                                         const float* __restrict__ sum,
                                                         const float* __restrict__ sumsq,
                                                         const float* __restrict__ gamma,
                                                         const float* __restrict__ beta,
                                                         int applyBN,
                                                         uint_t* __restrict__ ppack,
                                                         uint_t* __restrict__ qpack) {
    __shared__ __align__(16) ushort_t lbF[128 * BPAD * 8];
    __shared__ __align__(16) ushort_t lbS[128 * BPAD * 8];
    int pair = blockIdx.y;           // 0 -> (Pf,Ps), 1 -> (Qf,Qs)
    int wave = threadIdx.x >> 6;
    int lane = threadIdx.x & 63;
    int sub = lane & 15;
    int quad = lane >> 4;
    int m0 = blockIdx.x * 64 + wave * 16;
    int writeH = applyBN && (pair == 0);

    const ushort_t* whF = Wt + (size_t)(2 * pair) * 128 * H;       // f-gate table
    const ushort_t* whS = Wt + (size_t)(2 * pair + 1) * 128 * H;   // s-gate table

    // ---- stage both B tables into LDS (2048 16B-chunks each) ----
    for (int c = threadIdx.x; c < 2048; c += 256) {
        int n = c >> 4, k = c & 15;
        *(bf8_t*)(lbF + ((size_t)n * BPAD + k) * 8) = *(const bf8_t*)(whF + n * H + k * 8);
        *(bf8_t*)(lbS + ((size_t)n * BPAD + k) * 8) = *(const bf8_t*)(whS + n * H + k * 8);
    }

    // ---- A staging: fp32 h -> optional BN+ReLU -> bf16 hi/lo ----
    bf8_t aHi[4], aLo[4];
    int r = m0 + sub;
    int rc = r < NN ? r : NN - 1;
#pragma unroll
    for (int ks = 0; ks < 4; ++ks) {
        int kb = ks * 32 + quad * 8;
        const float* hp = hsrc + (size_t)rc * H + kb;
        float4 v0 = *(const float4*)hp;
        float4 v1 = *(const float4*)(hp + 4);
        float vv[8] = {v0.x, v0.y, v0.z, v0.w, v1.x, v1.y, v1.z, v1.w};
        if (applyBN) {
            float4 su0 = *(const float4*)&sum[kb],   su1 = *(const float4*)&sum[kb + 4];
            float4 sq0 = *(const float4*)&sumsq[kb], sq1 = *(const float4*)&sumsq[kb + 4];
            float4 ga0 = *(const float4*)&gamma[kb], ga1 = *(const float4*)&gamma[kb + 4];
            float4 be0 = *(const float4*)&beta[kb],  be1 = *(const float4*)&beta[kb + 4];
            float su[8] = {su0.x, su0.y, su0.z, su0.w, su1.x, su1.y, su1.z, su1.w};
            float sq[8] = {sq0.x, sq0.y, sq0.z, sq0.w, sq1.x, sq1.y, sq1.z, sq1.w};
            float ga[8] = {ga0.x, ga0.y, ga0.z, ga0.w, ga1.x, ga1.y, ga1.z, ga1.w};
            float be[8] = {be0.x, be0.y, be0.z, be0.w, be1.x, be1.y, be1.z, be1.w};
#pragma unroll
            for (int i = 0; i < 8; ++i) {
                float mu  = su[i] * (1.0f / NN);
                float var = sq[i] * (1.0f / NN) - mu * mu;
                float sc  = ga[i] * rsqrtf(var + BN_EPSF);
                float sh  = be[i] - mu * sc;
                float v = fmaf(vv[i], sc, sh);
                vv[i] = v > 0.0f ? v : 0.0f;
            }
        }
        bf8_t hi8, lo8;
#pragma unroll
        for (int i = 0; i < 8; ++i) {
            ushort_t hi = f2bf(vv[i]);
            hi8[i] = (short)hi;
            lo8[i] = (short)f2bf(vv[i] - bf2f(hi));
        }
        aHi[ks] = hi8;
        aLo[ks] = lo8;
        if (writeH && r < NN) {
            float* op = hbn + (size_t)r * H + kb;
            *(float4*)op = make_float4(vv[0], vv[1], vv[2], vv[3]);
            *(float4*)(op + 4) = make_float4(vv[4], vv[5], vv[6], vv[7]);
        }
    }
    __syncthreads();

    f4_t accF[8], accS[8];
#pragma unroll
    for (int b = 0; b < 8; ++b) { accF[b] = (f4_t){0.f, 0.f, 0.f, 0.f}; accS[b] = (f4_t){0.f, 0.f, 0.f, 0.f}; }

#pragma unroll
    for (int nt = 0; nt < 8; ++nt) {
#pragma unroll
        for (int ks = 0; ks < 4; ++ks) {
            size_t lo = ((size_t)(nt * 16 + sub) * BPAD + ks * 4 + quad) * 8;
            bf8_t bF = *(const bf8_t*)(lbF + lo);
            bf8_t bS = *(const bf8_t*)(lbS + lo);
            accF[nt] = __builtin_amdgcn_mfma_f32_16x16x32_bf16(aHi[ks], bF, accF[nt], 0, 0, 0);
            accF[nt] = __builtin_amdgcn_mfma_f32_16x16x32_bf16(aLo[ks], bF, accF[nt], 0, 0, 0);
            accS[nt] = __builtin_amdgcn_mfma_f32_16x16x32_bf16(aHi[ks], bS, accS[nt], 0, 0, 0);
            accS[nt] = __builtin_amdgcn_mfma_f32_16x16x32_bf16(aLo[ks], bS, accS[nt], 0, 0, 0);
        }
    }

    uint_t* outp = pair ? qpack : ppack;
#pragma unroll
    for (int nt = 0; nt < 8; ++nt) {
        int col = nt * 16 + sub;
#pragma unroll
        for (int rr = 0; rr < 4; ++rr) {
            int row = m0 + quad * 4 + rr;
            if (row < NN) {
                uint_t lo = f2bf(accF[nt][rr]);
                uint_t hi = f2bf(accS[nt][rr]);
                outp[(size_t)row * H + col] = lo | (hi << 16);
            }
        }
    }
}

// Edge-parallel segmented CSR aggregation; P and Q both gathered as packed
// bf16 pairs (uint2 per lane). Segment metadata precomputed (endmask, csr_inv).
__global__ __launch_bounds__(256) void agg_edge_kernel(const int4* __restrict__ csr_fe,
                                                       const int* __restrict__ csr_dst,
                                                       const float* __restrict__ csr_inv,
                                                       const unsigned* __restrict__ endmask,
                                                       const float* __restrict__ Wf,
                                                       const float* __restrict__ bf,
                                                       const float* __restrict__ Ws,
                                                       const float* __restrict__ bs,
                                                       const uint_t* __restrict__ ppack,
                                                       const uint_t* __restrict__ qpack,
                                                       float* __restrict__ h,
                                                       float* __restrict__ sum,
                                                       float* __restrict__ sumsq) {
    int tid = threadIdx.x;
    if (blockIdx.x == 0 && tid < H) { sum[tid] = 0.0f; sumsq[tid] = 0.0f; }
    int lane = tid & 63;
    int wv = tid >> 6;
    int base = (blockIdx.x * 4 + wv) * EPW;
    int c0 = 2 * lane;

    float2 wf0 = *(const float2*)&Wf[256 * H + c0];
    float2 wf1 = *(const float2*)&Wf[257 * H + c0];
    float2 wf2 = *(const float2*)&Wf[258 * H + c0];
    float2 ws0 = *(const float2*)&Ws[256 * H + c0];
    float2 ws1 = *(const float2*)&Ws[257 * H + c0];
    float2 ws2 = *(const float2*)&Ws[258 * H + c0];
    float2 bf2_ = *(const float2*)&bf[c0];
    float2 bs2_ = *(const float2*)&bs[c0];

    // lanes replicate 16 edge records 4x (broadcast reads)
    int4 fe = csr_fe[base + (lane & (EPW - 1))];
    int  dd = csr_dst[base + (lane & (EPW - 1))];
    int  ivr = __float_as_int(csr_inv[base + (lane & (EPW - 1))]);
    unsigned mword = endmask[base >> 5];
    unsigned mask = __builtin_amdgcn_readfirstlane((mword >> (base & 31)) & 0xFFFFu);

    uint2 q[8];
#pragma unroll
    for (int i = 0; i < 8; ++i) {
        int s = __builtin_amdgcn_readlane(fe.w, i);
        q[i] = *(const uint2*)&qpack[(size_t)s * H + c0];
    }

    int dcur = __builtin_amdgcn_readlane(dd, 0);
    uint2 ppc = *(const uint2*)&ppack[(size_t)dcur * H + c0];
    float pf0 = __uint_as_float(ppc.x << 16), ps0 = __uint_as_float(ppc.x & 0xFFFF0000u);
    float pf1 = __uint_as_float(ppc.y << 16), ps1 = __uint_as_float(ppc.y & 0xFFFF0000u);
    unsigned m = mask;
    int e0 = m ? __builtin_ctz(m) : EPW;
    int dnext = 0;
    uint2 ppN = ppc;
    if (e0 + 1 < EPW) {
        dnext = __builtin_amdgcn_readlane(dd, e0 + 1);
        ppN = *(const uint2*)&ppack[(size_t)dnext * H + c0];
    }

    float acc0 = 0.f, acc1 = 0.f;

#pragma unroll
    for (int tb = 0; tb < EPW; tb += 8) {
#pragma unroll
        for (int i = 0; i < 8; ++i) {
            int t = tb + i;
            float ex = __int_as_float(__builtin_amdgcn_readlane(fe.x, t));
            float ey = __int_as_float(__builtin_amdgcn_readlane(fe.y, t));
            float ez = __int_as_float(__builtin_amdgcn_readlane(fe.z, t));
            uint2 qq = q[i];
            if (t + 8 < EPW) {
                int s2 = __builtin_amdgcn_readlane(fe.w, t + 8);
                q[i] = *(const uint2*)&qpack[(size_t)s2 * H + c0];
            }
            float qf0 = __uint_as_float(qq.x << 16);
            float qs0 = __uint_as_float(qq.x & 0xFFFF0000u);
            float qf1 = __uint_as_float(qq.y << 16);
            float qs1 = __uint_as_float(qq.y & 0xFFFF0000u);
            float f0 = fmaf(ex, wf0.x, fmaf(ey, wf1.x, fmaf(ez, wf2.x, pf0 + bf2_.x + qf0)));
            float v0 = fmaf(ex, ws0.x, fmaf(ey, ws1.x, fmaf(ez, ws2.x, ps0 + bs2_.x + qs0)));
            float f1 = fmaf(ex, wf0.y, fmaf(ey, wf1.y, fmaf(ez, wf2.y, pf1 + bf2_.y + qf1)));
            float v1 = fmaf(ex, ws0.y, fmaf(ey, ws1.y, fmaf(ez, ws2.y, ps1 + bs2_.y + qs1)));
            float sig0 = __builtin_amdgcn_rcpf(1.0f + __expf(-f0));
            float sp0  = fmaxf(v0, 0.0f) + __logf(1.0f + __expf(-fabsf(v0)));
            float sig1 = __builtin_amdgcn_rcpf(1.0f + __expf(-f1));
            float sp1  = fmaxf(v1, 0.0f) + __logf(1.0f + __expf(-fabsf(v1)));
            acc0 = fmaf(sig0, sp0, acc0);
            acc1 = fmaf(sig1, sp1, acc1);
            if (mask & (1u << t)) {   // wave-uniform segment end (precomputed)
                float inv = __int_as_float(__builtin_amdgcn_readlane(ivr, t));
                atomicAdd(&h[(size_t)dcur * H + c0], acc0 * inv);
                atomicAdd(&h[(size_t)dcur * H + c0 + 1], acc1 * inv);
                acc0 = 0.f; acc1 = 0.f;
                dcur = dnext;
                pf0 = __uint_as_float(ppN.x << 16); ps0 = __uint_as_float(ppN.x & 0xFFFF0000u);
                pf1 = __uint_as_float(ppN.y << 16); ps1 = __uint_as_float(ppN.y & 0xFFFF0000u);
                m &= m - 1;
                int e1 = m ? __builtin_ctz(m) : EPW;
                if (e1 + 1 < EPW) {
                    dnext = __builtin_amdgcn_readlane(dd, e1 + 1);
                    ppN = *(const uint2*)&ppack[(size_t)dnext * H + c0];
                }
            }
        }
    }
    if (!(mask & (1u << (EPW - 1)))) {   // trailing partial segment
        float inv = __int_as_float(__builtin_amdgcn_readlane(ivr, EPW - 1));
        atomicAdd(&h[(size_t)dcur * H + c0], acc0 * inv);
        atomicAdd(&h[(size_t)dcur * H + c0 + 1], acc1 * inv);
    }
}

// per-column sum / sumsq; 8 independent row loads per iteration.
__global__ __launch_bounds__(H) void stats_kernel(const float* __restrict__ h,
                                                  float* __restrict__ sum,
                                                  float* __restrict__ sumsq) {
    int j = threadIdx.x;
    float s = 0.0f, ss = 0.0f;
    int n = blockIdx.x * 8;
    for (; n + 7 < NN; n += gridDim.x * 8) {
        float v[8];
#pragma unroll
        for (int i = 0; i < 8; ++i) v[i] = h[(size_t)(n + i) * H + j];
#pragma unroll
        for (int i = 0; i < 8; ++i) { s += v[i]; ss = fmaf(v[i], v[i], ss); }
    }
    for (; n < NN; ++n) {
        float v = h[(size_t)n * H + j];
        s += v;
        ss = fmaf(v, v, ss);
    }
    atomicAdd(&sum[j], s);
    atomicAdd(&sumsq[j], ss);
}

__global__ __launch_bounds__(H) void pool_kernel(const float* __restrict__ h,
                                                 const int* __restrict__ batch,
                                                 const float* __restrict__ sum,
                                                 const float* __restrict__ sumsq,
                                                 const float* __restrict__ gamma,
                                                 const float* __restrict__ beta,
                                                 float* __restrict__ g,
                                                 float* __restrict__ cnt) {
    int j = threadIdx.x;
    float mu  = sum[j] * (1.0f / NN);
    float var = sumsq[j] * (1.0f / NN) - mu * mu;
    float sc  = gamma[j] * rsqrtf(var + BN_EPSF);
    float sh  = beta[j] - mu * sc;
    for (int n = blockIdx.x; n < NN; n += gridDim.x) {
        int b = batch[n];
        float v = fmaf(h[(size_t)n * H + j], sc, sh);
        v = v > 0.0f ? v : 0.0f;
        atomicAdd(&g[(size_t)b * H + j], v);
        if (j == 0) atomicAdd(&cnt[b], 1.0f);
    }
}

__global__ __launch_bounds__(H) void mlp_kernel(const float* __restrict__ g,
                                                const float* __restrict__ cnt,
                                                const float* __restrict__ W1,
                                                const float* __restrict__ b1,
                                                const float* __restrict__ W2,
                                                const float* __restrict__ b2,
                                                const float* __restrict__ W3,
                                                const float* __restrict__ b3,
                                                float* __restrict__ out) {
    int gid = blockIdx.x, j = threadIdx.x;
    __shared__ float s1[H];
    __shared__ float s2[H];
    __shared__ float wsum[2];
    float c = cnt[gid];
    c = c < 1.0f ? 1.0f : c;
    s1[j] = g[gid * H + j] / c;
    __syncthreads();
    float a = b1[j];
    for (int k = 0; k < H; ++k) a = fmaf(s1[k], W1[k * H + j], a);
    a = a > 0.0f ? a : 0.0f;
    s2[j] = a;
    __syncthreads();
    float t = b2[j];
    for (int k = 0; k < H; ++k) t = fmaf(s2[k], W2[k * H + j], t);
    t = t > 0.0f ? t : 0.0f;
    float p = t * W3[j];
    for (int off = 32; off > 0; off >>= 1) p += __shfl_down(p, off, 64);
    if ((j & 63) == 0) wsum[j >> 6] = p;
    __syncthreads();
    if (j == 0) out[gid] = wsum[0] + wsum[1] + b3[0];
}

extern "C" void kernel_launch(void* const* d_in, const int* in_sizes, int n_in,
                              void* d_out, int out_size, void* d_ws, size_t ws_size,
                              hipStream_t stream) {
    const float* x     = (const float*)d_in[0];
    const int*   ei    = (const int*)d_in[1];
    const int*   srcp  = ei;        // edge_index[0] = source (x_j)
    const int*   dstp  = ei + NE;   // edge_index[1] = target (aggregation index)
    const int*   batch = (const int*)d_in[2];
    const float* ea    = (const float*)d_in[3];
    const float* Win   = (const float*)d_in[4];
    const float* bin   = (const float*)d_in[5];
    const float* Wf    = (const float*)d_in[6];
    const float* bf    = (const float*)d_in[7];
    const float* Ws    = (const float*)d_in[8];
    const float* bs    = (const float*)d_in[9];
    const float* gamma = (const float*)d_in[10];
    const float* beta  = (const float*)d_in[11];
    const float* W1    = (const float*)d_in[12];
    const float* b1    = (const float*)d_in[13];
    const float* W2    = (const float*)d_in[14];
    const float* b2    = (const float*)d_in[15];
    const float* W3    = (const float*)d_in[16];
    const float* b3    = (const float*)d_in[17];
    float* out = (float*)d_out;

    const size_t NH = (size_t)NN * H;
    float* wsp = (float*)d_ws;
    size_t off = 0;
    float* hA     = wsp + off; off += NH;
    float* hB     = wsp + off; off += NH;
    uint_t* ppack = (uint_t*)(wsp + off); off += NH;  // packed bf16 (Pf,Ps)
    uint_t* qpack = (uint_t*)(wsp + off); off += NH;  // packed bf16 (Qf,Qs)
    float* invdeg = wsp + off; off += NN;
    float* sum    = wsp + off; off += H;
    float* sumsq  = wsp + off; off += H;
    float* g      = wsp + off; off += (size_t)NG * H;
    float* cnt    = wsp + off; off += NG;
    off = (off + 3) & ~(size_t)3;
    float4* csr_ea4 = (float4*)(wsp + off); off += (size_t)NE * 4;
    float* csr_inv = wsp + off; off += NE;
    int* degi      = (int*)(wsp + off); off += NN;
    int* counter   = (int*)(wsp + off); off += 1;
    unsigned* endmask = (unsigned*)(wsp + off); off += NE / 32;
    int* cursor    = (int*)(wsp + off); off += NN;
    int* csr_dst   = (int*)(wsp + off); off += NE;
    off = (off + 3) & ~(size_t)3;
    ushort_t* Wt = (ushort_t*)(wsp + off); off += (size_t)NL * 512 * H / 2;

    // ---- CSR + weight prep (topology/weights fixed across layers) ----
    // zero degi + counter + endmask in one memset (contiguous)
    hipMemsetAsync(degi, 0, (NN + 1 + NE / 32) * sizeof(int), stream);
    deg_int_kernel<<<(NE + 255) / 256, 256, 0, stream>>>(dstp, degi);
    reserve_kernel<<<(NN + 255) / 256, 256, 0, stream>>>(degi, cursor, invdeg, counter);
    scatter_kernel<<<(NE + 255) / 256, 256, 0, stream>>>(srcp, dstp, ea, invdeg, cursor,
                                                         csr_ea4, csr_dst, csr_inv);
    flag_kernel<<<(NE + 255) / 256, 256, 0, stream>>>(csr_dst, endmask);
    wprep_kernel<<<(NL * 512 * H + 255) / 256, 256, 0, stream>>>(Wf, Ws, Wt);

    hin_kernel<<<NN, H, 0, stream>>>(x, Win, bin, hA);

    float* hRead = hA;
    for (int l = 0; l < NL; ++l) {
        float* hTgt = (l == 0) ? hA : ((l & 1) ? hB : hA);
        node_gemm_mfma<<<dim3((NN + 63) / 64, 2), 256, 0, stream>>>(
            hRead, hTgt,
            Wt + (size_t)l * 512 * H,
            sum, sumsq,
            gamma + (size_t)(l ? l - 1 : 0) * H,
            beta  + (size_t)(l ? l - 1 : 0) * H,
            l > 0, ppack, qpack);
        agg_edge_kernel<<<NE / (4 * EPW), 256, 0, stream>>>((const int4*)csr_ea4, csr_dst,
                                                            csr_inv, endmask,
                                                            Wf + (size_t)l * ZDH, bf + (size_t)l * H,
                                                            Ws + (size_t)l * ZDH, bs + (size_t)l * H,
                                                            ppack, qpack,
                                                            hTgt, sum, sumsq);
        stats_kernel<<<512, H, 0, stream>>>(hTgt, sum, sumsq);
        hRead = hTgt;
    }

    hipMemsetAsync(g, 0, ((size_t)NG * H + NG) * sizeof(float), stream);
    pool_kernel<<<2048, H, 0, stream>>>(hRead, batch, sum, sumsq,
                                        gamma + (size_t)(NL - 1) * H,
                                        beta + (size_t)(NL - 1) * H, g, cnt);
    mlp_kernel<<<NG, H, 0, stream>>>(g, cnt, W1, b1, W2, b2, W3, b3, out);
}